// Round 7
// baseline (2700.037 us; speedup 1.0000x reference)
//
#include <hip/hip_runtime.h>
#include <hip/hip_cooperative_groups.h>
#include <math.h>

namespace cg = cooperative_groups;

// ---------------------------------------------------------------------------
// GNN: 3x GatedGraphConv (C=32,64,128; 4 inner layers each) + BN + pool + MLP
// Round 22: ONE cooperative kernel per conv layer (8 serial dispatches ->
// 1 coop dispatch with grid.sync between gather/GRU phases; 4 iterations and
// ping-pong swap in-kernel). Device math byte-identical to r18 (931 us best).
// Rationale: ~40 serial dispatches x ~3-5us boundary cost ~= 100-200us of
// gaps; r21 proved mixing helps (1.35 TB/s) but phase-launch overhead ate it.
// Fallback: if hipLaunchCooperativeKernel errors (capture unsupported), run
// the exact r18 serial launches instead (worst case == r18).
// ---------------------------------------------------------------------------

#define EPS_BN 1e-5f

typedef short short8 __attribute__((ext_vector_type(8)));
typedef unsigned short u16x8 __attribute__((ext_vector_type(8)));
typedef float f32x4 __attribute__((ext_vector_type(4)));

__device__ __forceinline__ float elu_f(float v) {
    return v > 0.f ? v : expm1f(v);
}
__device__ __forceinline__ float sigmoid_f(float v) {
    return 1.f / (1.f + __expf(-v));
}
__device__ __forceinline__ float tanh_f(float v) {
    float e = __expf(2.f * v);
    return 1.f - 2.f / (e + 1.f);
}
__device__ __forceinline__ unsigned short f2bf(float f) {
    unsigned u = __float_as_uint(f);
    unsigned r = (u + 0x7FFF + ((u >> 16) & 1)) >> 16;
    return (unsigned short)r;
}
__device__ __forceinline__ float bf2f(unsigned short b) {
    return __uint_as_float(((unsigned)b) << 16);
}
__device__ __forceinline__ void put_hl(unsigned short* __restrict__ hi,
                                       unsigned short* __restrict__ lo,
                                       size_t idx, float v) {
    unsigned short h = f2bf(v);
    hi[idx] = h;
    lo[idx] = f2bf(v - bf2f(h));
}

// ------------------------- CSR construction -------------------------------

__global__ __launch_bounds__(256) void hist_kernel(
    const int* __restrict__ ei, int* __restrict__ deg, int E) {
    int e = blockIdx.x * 256 + threadIdx.x;
    if (e < E) atomicAdd(&deg[ei[E + e]], 1);
}

__global__ __launch_bounds__(256) void scan1_kernel(
    const int* __restrict__ deg, int* __restrict__ out,
    int* __restrict__ blockSums, int N) {
    __shared__ int sdata[256];
    int b = blockIdx.x, t = threadIdx.x;
    int base = b * 1024 + t * 4;
    int v[4], s = 0;
#pragma unroll
    for (int i = 0; i < 4; ++i) {
        v[i] = (base + i < N) ? deg[base + i] : 0;
        s += v[i];
    }
    sdata[t] = s;
    __syncthreads();
    for (int off = 1; off < 256; off <<= 1) {
        int x = (t >= off) ? sdata[t - off] : 0;
        __syncthreads();
        sdata[t] += x;
        __syncthreads();
    }
    int run = sdata[t] - s;
#pragma unroll
    for (int i = 0; i < 4; ++i) {
        if (base + i < N) out[base + i] = run;
        run += v[i];
    }
    if (t == 255) blockSums[b] = sdata[255];
}

__global__ void scan2_kernel(int* blockSums, int nb) {
    if (threadIdx.x == 0 && blockIdx.x == 0) {
        int run = 0;
        for (int i = 0; i < nb; ++i) {
            int v = blockSums[i];
            blockSums[i] = run;
            run += v;
        }
    }
}

__global__ __launch_bounds__(256) void scan3_kernel(
    const int* __restrict__ out, const int* __restrict__ blockSums,
    int* __restrict__ rowstart, int* __restrict__ writeptr, int N, int E) {
    int i = blockIdx.x * 256 + threadIdx.x;
    if (i < N) {
        int v = out[i] + blockSums[i >> 10];
        rowstart[i] = v;
        writeptr[i] = v;
    }
    if (i == 0) rowstart[N] = E;
}

__global__ __launch_bounds__(256) void fill_kernel(
    const int* __restrict__ ei, int* __restrict__ writeptr,
    int* __restrict__ csr_src, int E) {
    int e = blockIdx.x * 256 + threadIdx.x;
    if (e < E) {
        int d = ei[E + e];
        int p = atomicAdd(&writeptr[d], 1);
        csr_src[p] = ei[e];
    }
}

// ------------------------- Wc = W[l] @ wih^T ------------------------------

template <int C>
__global__ __launch_bounds__(256) void wc_kernel(
    const float* __restrict__ W, const float* __restrict__ wih,
    float* __restrict__ Wc) {
    int idx = blockIdx.x * 256 + threadIdx.x;
    if (idx >= 4 * C * 3 * C) return;
    int l = idx / (C * 3 * C);
    int r = idx % (C * 3 * C);
    int k = r / (3 * C);
    int row = r % (3 * C);
    const float* wrow = W + ((size_t)l * C + k) * C;
    const float* irow = wih + (size_t)row * C;
    float acc = 0.f;
#pragma unroll 4
    for (int t = 0; t < C; ++t) acc += wrow[t] * irow[t];
    Wc[idx] = acc;
}

// ------------------------- B2 swizzle (hi/lo, all 4 layers) ---------------
// mfma_f32_16x16x32_bf16:
//   A[m][k]: m = lane&15, k = (lane>>4)*8 + j
//   B[k][n]: n = lane&15, k = (lane>>4)*8 + j
//   C/D:     col = lane&15, row = (lane>>4)*4 + reg
// GRU concat-B: K = 2C (k<C: Wc_l on S; k>=C: whh on H).
// tslot per ks: [0,CT): r ; [CT,2CT): z ; [2CT,3CT): k<C ? in : hn

template <int C>
__global__ __launch_bounds__(256) void swizzle_b2_kernel(
    const float* __restrict__ Wc, const float* __restrict__ whh,
    unsigned short* __restrict__ BsHi, unsigned short* __restrict__ BsLo) {
    constexpr int CT = C / 16;
    int idx = blockIdx.x * 256 + threadIdx.x;
    if (idx >= 4 * 6 * C * C) return;
    int l = idx / (6 * C * C);
    int r0 = idx % (6 * C * C);
    int j = r0 & 7;
    int lane = (r0 >> 3) & 63;
    int rest = r0 >> 9;
    int tslot = rest % (3 * CT);
    int ks = rest / (3 * CT);
    int k = ks * 32 + (lane >> 4) * 8 + j;
    int g = tslot / CT;
    int lt = tslot % CT;
    int c = lt * 16 + (lane & 15);
    int row = g * C + c;
    float v = (k < C) ? Wc[((size_t)l * C + k) * 3 * C + row]
                      : whh[(size_t)row * C + (k - C)];
    unsigned short h = f2bf(v);
    BsHi[idx] = h;
    BsLo[idx] = f2bf(v - bf2f(h));
}

// ------------------------- device bodies (r18 math) -----------------------

template <int C>
__device__ __forceinline__ void gather_dev(
    const unsigned short* __restrict__ Xhi,
    const int* __restrict__ rowstart, const int* __restrict__ csr_src,
    unsigned short* __restrict__ Shi, int d0, int d1) {
    constexpr int LPG = C / 8;
    int lane = threadIdx.x % LPG;
    int grp = threadIdx.x / LPG;
    int d = d0 + grp;
    if (d >= d1) return;
    int p = rowstart[d];
    int p1 = rowstart[d + 1];
    float a[8];
#pragma unroll
    for (int j = 0; j < 8; ++j) a[j] = 0.f;
    int off = lane * 8;
    for (; p + 3 < p1; p += 4) {
        int s0 = csr_src[p];
        int s1 = csr_src[p + 1];
        int s2 = csr_src[p + 2];
        int s3 = csr_src[p + 3];
        u16x8 h0 = *(const u16x8*)(Xhi + (size_t)s0 * C + off);
        u16x8 h1 = *(const u16x8*)(Xhi + (size_t)s1 * C + off);
        u16x8 h2 = *(const u16x8*)(Xhi + (size_t)s2 * C + off);
        u16x8 h3 = *(const u16x8*)(Xhi + (size_t)s3 * C + off);
#pragma unroll
        for (int j = 0; j < 8; ++j) {
            a[j] += (bf2f(h0[j]) + bf2f(h1[j])) + (bf2f(h2[j]) + bf2f(h3[j]));
        }
    }
    for (; p < p1; ++p) {
        int s0 = csr_src[p];
        u16x8 h0 = *(const u16x8*)(Xhi + (size_t)s0 * C + off);
#pragma unroll
        for (int j = 0; j < 8; ++j) a[j] += bf2f(h0[j]);
    }
    size_t base = (size_t)d * C + off;
#pragma unroll
    for (int j = 0; j < 8; ++j) Shi[base + j] = f2bf(a[j]);
}

// GRU NT=TPW*16 nodes starting at node0; nodes valid in [0, nlim).
template <int C, int TPW>
__device__ __forceinline__ void gru_dev(
    const unsigned short* __restrict__ HinHi, const unsigned short* __restrict__ HinLo,
    unsigned short* __restrict__ HoutHi, unsigned short* __restrict__ HoutLo,
    const unsigned short* __restrict__ Shi,
    const unsigned short* __restrict__ BsHi, const unsigned short* __restrict__ BsLo,
    const float* __restrict__ biasI, const float* __restrict__ biasH,
    int node0, int nlim) {
    constexpr int CT = C / 16;
    constexpr int KS = C / 16;
    constexpr int CTW = CT / 4;
    int wave = threadIdx.x >> 6;
    int lane = threadIdx.x & 63;
    int quad = lane >> 4;
    int l16 = lane & 15;
    int arow[TPW];
#pragma unroll
    for (int t = 0; t < TPW; ++t) {
        int r = node0 + t * 16 + l16;
        arow[t] = r < nlim ? r : nlim - 1;
    }
    f32x4 accR[CTW][TPW], accZ[CTW][TPW], accN[CTW][TPW], accH[CTW][TPW];
#pragma unroll
    for (int ct = 0; ct < CTW; ++ct)
#pragma unroll
        for (int t = 0; t < TPW; ++t) {
            accR[ct][t] = (f32x4){0.f, 0.f, 0.f, 0.f};
            accZ[ct][t] = (f32x4){0.f, 0.f, 0.f, 0.f};
            accN[ct][t] = (f32x4){0.f, 0.f, 0.f, 0.f};
            accH[ct][t] = (f32x4){0.f, 0.f, 0.f, 0.f};
        }
    const short8* bhi = (const short8*)BsHi;
    const short8* blo = (const short8*)BsLo;

    for (int ks = 0; ks < KS / 2; ++ks) {
        int k0 = ks * 32 + quad * 8;
        short8 ahi[TPW];
#pragma unroll
        for (int t = 0; t < TPW; ++t)
            ahi[t] = *(const short8*)(Shi + (size_t)arow[t] * C + k0);
#pragma unroll
        for (int ct = 0; ct < CTW; ++ct) {
            int ts = ks * 3 * CT + wave * CTW + ct;
            short8 bhf = bhi[(size_t)ts * 64 + lane];
            short8 blf = blo[(size_t)ts * 64 + lane];
#pragma unroll
            for (int t = 0; t < TPW; ++t) {
                accR[ct][t] = __builtin_amdgcn_mfma_f32_16x16x32_bf16(ahi[t], bhf, accR[ct][t], 0, 0, 0);
                accR[ct][t] = __builtin_amdgcn_mfma_f32_16x16x32_bf16(ahi[t], blf, accR[ct][t], 0, 0, 0);
            }
            bhf = bhi[(size_t)(ts + CT) * 64 + lane];
            blf = blo[(size_t)(ts + CT) * 64 + lane];
#pragma unroll
            for (int t = 0; t < TPW; ++t) {
                accZ[ct][t] = __builtin_amdgcn_mfma_f32_16x16x32_bf16(ahi[t], bhf, accZ[ct][t], 0, 0, 0);
                accZ[ct][t] = __builtin_amdgcn_mfma_f32_16x16x32_bf16(ahi[t], blf, accZ[ct][t], 0, 0, 0);
            }
            bhf = bhi[(size_t)(ts + 2 * CT) * 64 + lane];
            blf = blo[(size_t)(ts + 2 * CT) * 64 + lane];
#pragma unroll
            for (int t = 0; t < TPW; ++t) {
                accN[ct][t] = __builtin_amdgcn_mfma_f32_16x16x32_bf16(ahi[t], bhf, accN[ct][t], 0, 0, 0);
                accN[ct][t] = __builtin_amdgcn_mfma_f32_16x16x32_bf16(ahi[t], blf, accN[ct][t], 0, 0, 0);
            }
        }
    }
    for (int ks = KS / 2; ks < KS; ++ks) {
        int k0 = ks * 32 + quad * 8 - C;
        short8 ahi[TPW], alo[TPW];
#pragma unroll
        for (int t = 0; t < TPW; ++t) {
            ahi[t] = *(const short8*)(HinHi + (size_t)arow[t] * C + k0);
            alo[t] = *(const short8*)(HinLo + (size_t)arow[t] * C + k0);
        }
#pragma unroll
        for (int ct = 0; ct < CTW; ++ct) {
            int ts = ks * 3 * CT + wave * CTW + ct;
            short8 bhf = bhi[(size_t)ts * 64 + lane];
            short8 blf = blo[(size_t)ts * 64 + lane];
#pragma unroll
            for (int t = 0; t < TPW; ++t) {
                accR[ct][t] = __builtin_amdgcn_mfma_f32_16x16x32_bf16(ahi[t], bhf, accR[ct][t], 0, 0, 0);
                accR[ct][t] = __builtin_amdgcn_mfma_f32_16x16x32_bf16(alo[t], bhf, accR[ct][t], 0, 0, 0);
                accR[ct][t] = __builtin_amdgcn_mfma_f32_16x16x32_bf16(ahi[t], blf, accR[ct][t], 0, 0, 0);
            }
            bhf = bhi[(size_t)(ts + CT) * 64 + lane];
            blf = blo[(size_t)(ts + CT) * 64 + lane];
#pragma unroll
            for (int t = 0; t < TPW; ++t) {
                accZ[ct][t] = __builtin_amdgcn_mfma_f32_16x16x32_bf16(ahi[t], bhf, accZ[ct][t], 0, 0, 0);
                accZ[ct][t] = __builtin_amdgcn_mfma_f32_16x16x32_bf16(alo[t], bhf, accZ[ct][t], 0, 0, 0);
                accZ[ct][t] = __builtin_amdgcn_mfma_f32_16x16x32_bf16(ahi[t], blf, accZ[ct][t], 0, 0, 0);
            }
            bhf = bhi[(size_t)(ts + 2 * CT) * 64 + lane];
            blf = blo[(size_t)(ts + 2 * CT) * 64 + lane];
#pragma unroll
            for (int t = 0; t < TPW; ++t) {
                accH[ct][t] = __builtin_amdgcn_mfma_f32_16x16x32_bf16(ahi[t], bhf, accH[ct][t], 0, 0, 0);
                accH[ct][t] = __builtin_amdgcn_mfma_f32_16x16x32_bf16(alo[t], bhf, accH[ct][t], 0, 0, 0);
                accH[ct][t] = __builtin_amdgcn_mfma_f32_16x16x32_bf16(ahi[t], blf, accH[ct][t], 0, 0, 0);
            }
        }
    }

#pragma unroll
    for (int ct = 0; ct < CTW; ++ct) {
        int c = (wave * CTW + ct) * 16 + l16;
        float bir = biasI[c], biz = biasI[C + c], bin = biasI[2 * C + c];
        float bhr = biasH[c], bhz = biasH[C + c], bhn = biasH[2 * C + c];
#pragma unroll
        for (int t = 0; t < TPW; ++t) {
#pragma unroll
            for (int r = 0; r < 4; ++r) {
                int node = node0 + t * 16 + quad * 4 + r;
                if (node < nlim) {
                    size_t gi = (size_t)node * C + c;
                    float xo = bf2f(HinHi[gi]) + bf2f(HinLo[gi]);
                    float rv = sigmoid_f(accR[ct][t][r] + bir + bhr);
                    float zv = sigmoid_f(accZ[ct][t][r] + biz + bhz);
                    float nv = tanh_f(accN[ct][t][r] + bin + rv * (accH[ct][t][r] + bhn));
                    put_hl(HoutHi, HoutLo, gi, (1.f - zv) * nv + zv * xo);
                }
            }
        }
    }
}

__device__ __forceinline__ void gru32_dev(
    const unsigned short* __restrict__ HinHi, const unsigned short* __restrict__ HinLo,
    unsigned short* __restrict__ HoutHi, unsigned short* __restrict__ HoutLo,
    const unsigned short* __restrict__ Shi,
    const unsigned short* __restrict__ BsHi, const unsigned short* __restrict__ BsLo,
    const float* __restrict__ biasI, const float* __restrict__ biasH,
    int blk0, int nlim) {
    constexpr int C = 32;
    constexpr int CT = 2;
    int wave = threadIdx.x >> 6;
    int lane = threadIdx.x & 63;
    int quad = lane >> 4;
    int l16 = lane & 15;
    int node0 = blk0 + wave * 16;
    int ar = node0 + l16;
    if (ar >= nlim) ar = nlim - 1;
    f32x4 accR[CT], accZ[CT], accN[CT], accH[CT];
#pragma unroll
    for (int t = 0; t < CT; ++t) {
        accR[t] = (f32x4){0.f, 0.f, 0.f, 0.f};
        accZ[t] = (f32x4){0.f, 0.f, 0.f, 0.f};
        accN[t] = (f32x4){0.f, 0.f, 0.f, 0.f};
        accH[t] = (f32x4){0.f, 0.f, 0.f, 0.f};
    }
    const short8* bhi = (const short8*)BsHi;
    const short8* blo = (const short8*)BsLo;
    int k0 = quad * 8;
    {
        short8 ahi = *(const short8*)(Shi + (size_t)ar * C + k0);
#pragma unroll
        for (int g = 0; g < 3; ++g) {
            f32x4* acc = g == 0 ? accR : (g == 1 ? accZ : accN);
#pragma unroll
            for (int t = 0; t < CT; ++t) {
                int ts = g * CT + t;
                short8 bhf = bhi[(size_t)ts * 64 + lane];
                short8 blf = blo[(size_t)ts * 64 + lane];
                acc[t] = __builtin_amdgcn_mfma_f32_16x16x32_bf16(ahi, bhf, acc[t], 0, 0, 0);
                acc[t] = __builtin_amdgcn_mfma_f32_16x16x32_bf16(ahi, blf, acc[t], 0, 0, 0);
            }
        }
    }
    {
        short8 ahi = *(const short8*)(HinHi + (size_t)ar * C + k0);
        short8 alo = *(const short8*)(HinLo + (size_t)ar * C + k0);
#pragma unroll
        for (int g = 0; g < 3; ++g) {
            f32x4* acc = g == 0 ? accR : (g == 1 ? accZ : accH);
#pragma unroll
            for (int t = 0; t < CT; ++t) {
                int ts = 3 * CT + g * CT + t;
                short8 bhf = bhi[(size_t)ts * 64 + lane];
                short8 blf = blo[(size_t)ts * 64 + lane];
                acc[t] = __builtin_amdgcn_mfma_f32_16x16x32_bf16(ahi, bhf, acc[t], 0, 0, 0);
                acc[t] = __builtin_amdgcn_mfma_f32_16x16x32_bf16(alo, bhf, acc[t], 0, 0, 0);
                acc[t] = __builtin_amdgcn_mfma_f32_16x16x32_bf16(ahi, blf, acc[t], 0, 0, 0);
            }
        }
    }
#pragma unroll
    for (int t = 0; t < CT; ++t) {
        int c = t * 16 + l16;
        float bir = biasI[c], biz = biasI[C + c], bin = biasI[2 * C + c];
        float bhr = biasH[c], bhz = biasH[C + c], bhn = biasH[2 * C + c];
#pragma unroll
        for (int r = 0; r < 4; ++r) {
            int node = node0 + quad * 4 + r;
            if (node < nlim) {
                size_t gi = (size_t)node * C + c;
                float xo = bf2f(HinHi[gi]) + bf2f(HinLo[gi]);
                float rv = sigmoid_f(accR[t][r] + bir + bhr);
                float zv = sigmoid_f(accZ[t][r] + biz + bhz);
                float nv = tanh_f(accN[t][r] + bin + rv * (accH[t][r] + bhn));
                put_hl(HoutHi, HoutLo, gi, (1.f - zv) * nv + zv * xo);
            }
        }
    }
}

// ------------------------- cooperative conv kernel ------------------------
// Grid-stride gather phase -> grid.sync -> grid-stride GRU phase -> grid.sync
// x4 iterations, ping-pong swap in-kernel. Byte-identical math to r18.

template <int C, int TPW>
__global__ __launch_bounds__(256, 3) void conv_coop_kernel(
    unsigned short* Ahi, unsigned short* Alo,
    unsigned short* Bhi, unsigned short* Blo,
    unsigned short* Shi,
    const int* rowstart, const int* csr_src,
    const unsigned short* BsHi, const unsigned short* BsLo,
    const float* biasI, const float* biasH, int N) {
    cg::grid_group grid = cg::this_grid();
    constexpr int GPB = 2048 / C;
    constexpr int NT = TPW * 16;
    int gblocks = (N + GPB - 1) / GPB;
    int rblocks = (N + NT - 1) / NT;
    unsigned short *inHi = Ahi, *inLo = Alo, *outHi = Bhi, *outLo = Blo;
#pragma unroll 1
    for (int it = 0; it < 4; ++it) {
#pragma unroll 1
        for (int vb = blockIdx.x; vb < gblocks; vb += gridDim.x)
            gather_dev<C>(inHi, rowstart, csr_src, Shi, vb * GPB, N);
        grid.sync();
        const unsigned short* bs_h = BsHi + (size_t)it * 6 * C * C;
        const unsigned short* bs_l = BsLo + (size_t)it * 6 * C * C;
#pragma unroll 1
        for (int vb = blockIdx.x; vb < rblocks; vb += gridDim.x) {
            if constexpr (C == 32)
                gru32_dev(inHi, inLo, outHi, outLo, Shi, bs_h, bs_l,
                          biasI, biasH, vb * NT, N);
            else
                gru_dev<C, TPW>(inHi, inLo, outHi, outLo, Shi, bs_h, bs_l,
                                biasI, biasH, vb * NT, N);
        }
        grid.sync();
        unsigned short* tp;
        tp = inHi; inHi = outHi; outHi = tp;
        tp = inLo; inLo = outLo; outLo = tp;
    }
}

// ------------------------- serial fallback kernels (r18) ------------------

template <int C>
__global__ __launch_bounds__(256) void gather_kernel(
    const unsigned short* __restrict__ Xhi,
    const int* __restrict__ rowstart, const int* __restrict__ csr_src,
    unsigned short* __restrict__ Shi, int N) {
    constexpr int GPB = 2048 / C;
    gather_dev<C>(Xhi, rowstart, csr_src, Shi, blockIdx.x * GPB, N);
}

template <int C, int TPW>
__global__ __launch_bounds__(256, 3) void gru_mfma_kernel(
    const unsigned short* __restrict__ HinHi, const unsigned short* __restrict__ HinLo,
    unsigned short* __restrict__ HoutHi, unsigned short* __restrict__ HoutLo,
    const unsigned short* __restrict__ Shi,
    const unsigned short* __restrict__ BsHi, const unsigned short* __restrict__ BsLo,
    const float* __restrict__ biasI, const float* __restrict__ biasH, int N) {
    gru_dev<C, TPW>(HinHi, HinLo, HoutHi, HoutLo, Shi, BsHi, BsLo,
                    biasI, biasH, blockIdx.x * TPW * 16, N);
}

__global__ __launch_bounds__(256, 4) void gru32_kernel(
    const unsigned short* __restrict__ HinHi, const unsigned short* __restrict__ HinLo,
    unsigned short* __restrict__ HoutHi, unsigned short* __restrict__ HoutLo,
    const unsigned short* __restrict__ Shi,
    const unsigned short* __restrict__ BsHi, const unsigned short* __restrict__ BsLo,
    const float* __restrict__ biasI, const float* __restrict__ biasH, int N) {
    gru32_dev(HinHi, HinLo, HoutHi, HoutLo, Shi, BsHi, BsLo,
              biasI, biasH, blockIdx.x * 64, N);
}

// ------------------------- epilogues --------------------------------------

__global__ __launch_bounds__(256) void init_x_kernel(
    const float* __restrict__ x, unsigned short* __restrict__ Hhi,
    unsigned short* __restrict__ Hlo, int total) {
    int t = blockIdx.x * 256 + threadIdx.x;
    if (t < total) put_hl(Hhi, Hlo, t, x[t]);
}

template <int Cin, int Cout>
__global__ __launch_bounds__(256) void elu_bn_pad_kernel(
    const unsigned short* __restrict__ Shi, const unsigned short* __restrict__ Slo,
    unsigned short* __restrict__ Dhi, unsigned short* __restrict__ Dlo,
    const float* __restrict__ gamma, const float* __restrict__ beta,
    const float* __restrict__ mean, const float* __restrict__ var, int N) {
    long t = (long)blockIdx.x * 256 + threadIdx.x;
    long total = (long)N * Cout;
    if (t >= total) return;
    int n = (int)(t / Cout);
    int c = (int)(t & (Cout - 1));
    float v = 0.f;
    if (c < Cin) {
        size_t si = (size_t)n * Cin + c;
        float x = bf2f(Shi[si]) + bf2f(Slo[si]);
        x = elu_f(x);
        v = (x - mean[c]) * rsqrtf(var[c] + EPS_BN) * gamma[c] + beta[c];
    }
    put_hl(Dhi, Dlo, t, v);
}

__global__ __launch_bounds__(256) void pool_elu_kernel(
    const unsigned short* __restrict__ Hhi, const unsigned short* __restrict__ Hlo,
    const int* __restrict__ batch, float* __restrict__ G, int N) {
    long t = (long)blockIdx.x * 256 + threadIdx.x;
    if (t >= (long)N * 128) return;
    int n = (int)(t >> 7);
    int c = (int)(t & 127);
    float v = elu_f(bf2f(Hhi[t]) + bf2f(Hlo[t]));
    atomicAdd(&G[batch[n] * 128 + c], v);
}

__global__ __launch_bounds__(256) void fc1_kernel(
    const float* __restrict__ G, const float* __restrict__ W,
    const float* __restrict__ b, float* __restrict__ G2) {
    __shared__ float row[128];
    int g = blockIdx.x;
    int j = threadIdx.x;
    if (j < 128) row[j] = G[g * 128 + j];
    __syncthreads();
    float acc = b[j];
    for (int k = 0; k < 128; ++k) acc += row[k] * W[j * 128 + k];
    G2[g * 256 + j] = elu_f(acc);
}

__global__ __launch_bounds__(64) void fc2_logsoftmax_kernel(
    const float* __restrict__ G2, const float* __restrict__ W,
    const float* __restrict__ b, float* __restrict__ out) {
    __shared__ float row[256];
    __shared__ float logits[10];
    __shared__ float red[2];
    int g = blockIdx.x;
    int tid = threadIdx.x;
    for (int i = tid; i < 256; i += 64) row[i] = G2[g * 256 + i];
    __syncthreads();
    if (tid < 10) {
        float acc = b[tid];
        for (int k = 0; k < 256; ++k) acc += row[k] * W[tid * 256 + k];
        logits[tid] = acc;
    }
    __syncthreads();
    if (tid == 0) {
        float m = -1e30f;
        for (int a = 0; a < 10; ++a) m = fmaxf(m, logits[a]);
        float s = 0.f;
        for (int a = 0; a < 10; ++a) s += expf(logits[a] - m);
        red[0] = m;
        red[1] = logf(s);
    }
    __syncthreads();
    if (tid < 10) out[g * 10 + tid] = logits[tid] - red[0] - red[1];
}

// ---------------------------------------------------------------------------

template <int C, int TPW>
static void run_conv(unsigned short* Ahi, unsigned short* Alo,
                     unsigned short* Bhi, unsigned short* Blo,
                     unsigned short* Shi,
                     float* Wc, unsigned short* BsHi, unsigned short* BsLo,
                     const float* W, const float* wih, const float* whh,
                     const float* bih, const float* bhh,
                     const int* rowstart, const int* csr_src,
                     int N, int E, hipStream_t stream) {
    wc_kernel<C><<<(4 * C * 3 * C + 255) / 256, 256, 0, stream>>>(W, wih, Wc);
    swizzle_b2_kernel<C><<<(4 * 6 * C * C + 255) / 256, 256, 0, stream>>>(Wc, whh, BsHi, BsLo);
    constexpr int GPB = 2048 / C;
    constexpr int NT = TPW * 16;
    int gblocks = (N + GPB - 1) / GPB;
    int rblocks = (N + NT - 1) / NT;

    // ---- try one cooperative kernel for the whole 4-iteration ladder ----
    static int nblk = -2;  // per-instantiation occupancy cache
    if (nblk == -2) {
        nblk = -1;
        hipOccupancyMaxActiveBlocksPerMultiprocessor(
            &nblk, conv_coop_kernel<C, TPW>, 256, 0);
    }
    if (nblk >= 1) {
        int G = nblk * 256;  // 256 CUs on MI355X
        int maxvb = gblocks > rblocks ? gblocks : rblocks;
        if (G > maxvb) G = maxvb;
        unsigned short *a0 = Ahi, *a1 = Alo, *b0 = Bhi, *b1 = Blo, *s0 = Shi;
        const int *rs = rowstart, *cs = csr_src;
        const unsigned short *bh = BsHi, *bl = BsLo;
        const float *bi = bih, *bhh2 = bhh;
        int n = N;
        void* args[] = {&a0, &a1, &b0, &b1, &s0, &rs, &cs, &bh, &bl, &bi, &bhh2, &n};
        if (hipLaunchCooperativeKernel((const void*)conv_coop_kernel<C, TPW>,
                                       dim3(G), dim3(256), args, 0, stream) == hipSuccess)
            return;  // 4 iterations done; even count -> state back in (Ahi, Alo)
    }

    // ---- fallback: exact r18 serial ladder ----
    unsigned short *inHi = Ahi, *inLo = Alo, *outHi = Bhi, *outLo = Blo;
    for (int it = 0; it < 4; ++it) {
        gather_kernel<C><<<gblocks, 256, 0, stream>>>(
            inHi, rowstart, csr_src, Shi, N);
        const unsigned short* bs_h = BsHi + (size_t)it * 6 * C * C;
        const unsigned short* bs_l = BsLo + (size_t)it * 6 * C * C;
        if constexpr (C == 32)
            gru32_kernel<<<rblocks, 256, 0, stream>>>(
                inHi, inLo, outHi, outLo, Shi, bs_h, bs_l, bih, bhh, N);
        else
            gru_mfma_kernel<C, TPW><<<rblocks, 256, 0, stream>>>(
                inHi, inLo, outHi, outLo, Shi, bs_h, bs_l, bih, bhh, N);
        unsigned short* tp;
        tp = inHi; inHi = outHi; outHi = tp;
        tp = inLo; inLo = outLo; outLo = tp;
    }
}

extern "C" void kernel_launch(void* const* d_in, const int* in_sizes, int n_in,
                              void* d_out, int out_size, void* d_ws, size_t ws_size,
                              hipStream_t stream) {
    const float* x = (const float*)d_in[0];
    const int* ei = (const int*)d_in[1];
    const int* batch = (const int*)d_in[2];
    const float* fc1W = (const float*)d_in[3];
    const float* fc1b = (const float*)d_in[4];
    const float* fc2W = (const float*)d_in[5];
    const float* fc2b = (const float*)d_in[6];
    const float* c1W = (const float*)d_in[7];
    const float* c1wih = (const float*)d_in[8];
    const float* c1whh = (const float*)d_in[9];
    const float* c1bih = (const float*)d_in[10];
    const float* c1bhh = (const float*)d_in[11];
    const float* c2W = (const float*)d_in[12];
    const float* c2wih = (const float*)d_in[13];
    const float* c2whh = (const float*)d_in[14];
    const float* c2bih = (const float*)d_in[15];
    const float* c2bhh = (const float*)d_in[16];
    const float* c3W = (const float*)d_in[17];
    const float* c3wih = (const float*)d_in[18];
    const float* c3whh = (const float*)d_in[19];
    const float* c3bih = (const float*)d_in[20];
    const float* c3bhh = (const float*)d_in[21];
    const float* bn1g = (const float*)d_in[22];
    const float* bn1b = (const float*)d_in[23];
    const float* bn1m = (const float*)d_in[24];
    const float* bn1v = (const float*)d_in[25];
    const float* bn2g = (const float*)d_in[26];
    const float* bn2b = (const float*)d_in[27];
    const float* bn2m = (const float*)d_in[28];
    const float* bn2v = (const float*)d_in[29];

    int N = in_sizes[0] / 32;
    int E = in_sizes[1] / 2;

    const size_t NB = (size_t)N * 128;  // shorts per plane
    unsigned short* PAhi = (unsigned short*)d_ws;  // state pair A
    unsigned short* PAlo = PAhi + NB;
    unsigned short* PBhi = PAlo + NB;              // state pair B (ping-pong)
    unsigned short* PBlo = PBhi + NB;
    unsigned short* Shi = PBlo + NB;               // gathered-S (hi-only)
    unsigned short* Slo = Shi + NB;                // (unused; kept for layout)
    unsigned short* BsHi = Slo + NB;               // 4 layers x 6*C*C <= 393216
    unsigned short* BsLo = BsHi + 393216;
    float* Wc = (float*)(BsLo + 393216);           // 4*C*3C <= 196608 floats
    float* G = Wc + 196608;
    float* G2 = G + 32768;
    int* deg = (int*)(G2 + 65536);
    int* scanout = deg + N;
    int* rowstart = scanout + N;
    int* writeptr = rowstart + N + 1;
    int* blockSums = writeptr + N;
    int* csr_src = blockSums + 64;

    // ---- build CSR by dst (once; reused by all 12 propagation steps) ----
    hipMemsetAsync(deg, 0, (size_t)N * sizeof(int), stream);
    int eblocks = (E + 255) / 256;
    hist_kernel<<<eblocks, 256, 0, stream>>>(ei, deg, E);
    int nscan = (N + 1023) / 1024;
    scan1_kernel<<<nscan, 256, 0, stream>>>(deg, scanout, blockSums, N);
    scan2_kernel<<<1, 64, 0, stream>>>(blockSums, nscan);
    scan3_kernel<<<(N + 255) / 256, 256, 0, stream>>>(scanout, blockSums, rowstart, writeptr, N, E);
    fill_kernel<<<eblocks, 256, 0, stream>>>(ei, writeptr, csr_src, E);

    // x -> pair A hi/lo ([N,32])
    init_x_kernel<<<(N * 32 + 255) / 256, 256, 0, stream>>>(x, PAhi, PAlo, N * 32);

    // conv1 (C=32): state PA, ping-pong with PB
    run_conv<32, 4>(PAhi, PAlo, PBhi, PBlo, Shi, Wc, BsHi, BsLo,
                    c1W, c1wih, c1whh, c1bih, c1bhh, rowstart, csr_src, N, E, stream);
    elu_bn_pad_kernel<32, 64><<<(int)(((long)N * 64 + 255) / 256), 256, 0, stream>>>(
        PAhi, PAlo, PBhi, PBlo, bn1g, bn1b, bn1m, bn1v, N);

    // conv2 (C=64): state PB, ping-pong with PA (NT=64 as in r18)
    run_conv<64, 4>(PBhi, PBlo, PAhi, PAlo, Shi, Wc, BsHi, BsLo,
                    c2W, c2wih, c2whh, c2bih, c2bhh, rowstart, csr_src, N, E, stream);
    elu_bn_pad_kernel<64, 128><<<(int)(((long)N * 128 + 255) / 256), 256, 0, stream>>>(
        PBhi, PBlo, PAhi, PAlo, bn2g, bn2b, bn2m, bn2v, N);

    // conv3 (C=128): state PA, ping-pong with PB (NT=32 as in r18)
    run_conv<128, 2>(PAhi, PAlo, PBhi, PBlo, Shi, Wc, BsHi, BsLo,
                     c3W, c3wih, c3whh, c3bih, c3bhh, rowstart, csr_src, N, E, stream);

    // pool (reads pair A, stride 128)
    hipMemsetAsync(G, 0, 256 * 128 * sizeof(float), stream);
    pool_elu_kernel<<<(int)(((long)N * 128 + 255) / 256), 256, 0, stream>>>(
        PAhi, PAlo, batch, G, N);

    fc1_kernel<<<256, 256, 0, stream>>>(G, fc1W, fc1b, G2);
    fc2_logsoftmax_kernel<<<256, 64, 0, stream>>>(G2, fc2W, fc2b, (float*)d_out);
}

// Round 9
// 862.924 us; speedup vs baseline: 3.1289x; 3.1289x over previous
//
#include <hip/hip_runtime.h>
#include <math.h>

// ---------------------------------------------------------------------------
// GNN: 3x GatedGraphConv (C=32,64,128; 4 inner layers each) + BN + pool + MLP
// Round 24: split-precision B. r23 (B hi-only everywhere) failed absmax
// 4.75>1.87. Error decomposition: dropped S-half term B_lo*S scales with
// |S|~4 (sum of ~16 neighbors) => ~0.009/entry; dropped H-half term
// B_lo*H_hi ~0.0023 (|H|~1). So: S-half KEEPS B hi+lo (2 MFMA/acc, = r18);
// H-half drops B-lo (A=H hi+lo, B=hi: 2 MFMA/acc, keeps only the small term).
// MFMA 240->192/wave (-20%), B-load clusters 96->72 (-25%, the r18/r19-
// identified latency binder). All else byte-identical to r18 (931 us).
// ---------------------------------------------------------------------------

#define EPS_BN 1e-5f

typedef short short8 __attribute__((ext_vector_type(8)));
typedef unsigned short u16x8 __attribute__((ext_vector_type(8)));
typedef float f32x4 __attribute__((ext_vector_type(4)));

__device__ __forceinline__ float elu_f(float v) {
    return v > 0.f ? v : expm1f(v);
}
__device__ __forceinline__ float sigmoid_f(float v) {
    return 1.f / (1.f + __expf(-v));
}
__device__ __forceinline__ float tanh_f(float v) {
    float e = __expf(2.f * v);
    return 1.f - 2.f / (e + 1.f);
}
__device__ __forceinline__ unsigned short f2bf(float f) {
    unsigned u = __float_as_uint(f);
    unsigned r = (u + 0x7FFF + ((u >> 16) & 1)) >> 16;
    return (unsigned short)r;
}
__device__ __forceinline__ float bf2f(unsigned short b) {
    return __uint_as_float(((unsigned)b) << 16);
}
__device__ __forceinline__ void put_hl(unsigned short* __restrict__ hi,
                                       unsigned short* __restrict__ lo,
                                       size_t idx, float v) {
    unsigned short h = f2bf(v);
    hi[idx] = h;
    lo[idx] = f2bf(v - bf2f(h));
}

// ------------------------- CSR construction -------------------------------

__global__ __launch_bounds__(256) void hist_kernel(
    const int* __restrict__ ei, int* __restrict__ deg, int E) {
    int e = blockIdx.x * 256 + threadIdx.x;
    if (e < E) atomicAdd(&deg[ei[E + e]], 1);
}

__global__ __launch_bounds__(256) void scan1_kernel(
    const int* __restrict__ deg, int* __restrict__ out,
    int* __restrict__ blockSums, int N) {
    __shared__ int sdata[256];
    int b = blockIdx.x, t = threadIdx.x;
    int base = b * 1024 + t * 4;
    int v[4], s = 0;
#pragma unroll
    for (int i = 0; i < 4; ++i) {
        v[i] = (base + i < N) ? deg[base + i] : 0;
        s += v[i];
    }
    sdata[t] = s;
    __syncthreads();
    for (int off = 1; off < 256; off <<= 1) {
        int x = (t >= off) ? sdata[t - off] : 0;
        __syncthreads();
        sdata[t] += x;
        __syncthreads();
    }
    int run = sdata[t] - s;
#pragma unroll
    for (int i = 0; i < 4; ++i) {
        if (base + i < N) out[base + i] = run;
        run += v[i];
    }
    if (t == 255) blockSums[b] = sdata[255];
}

__global__ void scan2_kernel(int* blockSums, int nb) {
    if (threadIdx.x == 0 && blockIdx.x == 0) {
        int run = 0;
        for (int i = 0; i < nb; ++i) {
            int v = blockSums[i];
            blockSums[i] = run;
            run += v;
        }
    }
}

__global__ __launch_bounds__(256) void scan3_kernel(
    const int* __restrict__ out, const int* __restrict__ blockSums,
    int* __restrict__ rowstart, int* __restrict__ writeptr, int N, int E) {
    int i = blockIdx.x * 256 + threadIdx.x;
    if (i < N) {
        int v = out[i] + blockSums[i >> 10];
        rowstart[i] = v;
        writeptr[i] = v;
    }
    if (i == 0) rowstart[N] = E;
}

__global__ __launch_bounds__(256) void fill_kernel(
    const int* __restrict__ ei, int* __restrict__ writeptr,
    int* __restrict__ csr_src, int E) {
    int e = blockIdx.x * 256 + threadIdx.x;
    if (e < E) {
        int d = ei[E + e];
        int p = atomicAdd(&writeptr[d], 1);
        csr_src[p] = ei[e];
    }
}

// ------------------------- Wc = W[l] @ wih^T ------------------------------

template <int C>
__global__ __launch_bounds__(256) void wc_kernel(
    const float* __restrict__ W, const float* __restrict__ wih,
    float* __restrict__ Wc) {
    int idx = blockIdx.x * 256 + threadIdx.x;
    if (idx >= 4 * C * 3 * C) return;
    int l = idx / (C * 3 * C);
    int r = idx % (C * 3 * C);
    int k = r / (3 * C);
    int row = r % (3 * C);
    const float* wrow = W + ((size_t)l * C + k) * C;
    const float* irow = wih + (size_t)row * C;
    float acc = 0.f;
#pragma unroll 4
    for (int t = 0; t < C; ++t) acc += wrow[t] * irow[t];
    Wc[idx] = acc;
}

// ------------------------- B2 swizzle (hi/lo, all 4 layers) ---------------
// mfma_f32_16x16x32_bf16:
//   A[m][k]: m = lane&15, k = (lane>>4)*8 + j
//   B[k][n]: n = lane&15, k = (lane>>4)*8 + j
//   C/D:     col = lane&15, row = (lane>>4)*4 + reg
// GRU concat-B: K = 2C (k<C: Wc_l on S; k>=C: whh on H).
// tslot per ks: [0,CT): r ; [CT,2CT): z ; [2CT,3CT): k<C ? in : hn
// BsLo only consumed for k<C (S-half) since r24.

template <int C>
__global__ __launch_bounds__(256) void swizzle_b2_kernel(
    const float* __restrict__ Wc, const float* __restrict__ whh,
    unsigned short* __restrict__ BsHi, unsigned short* __restrict__ BsLo) {
    constexpr int CT = C / 16;
    int idx = blockIdx.x * 256 + threadIdx.x;
    if (idx >= 4 * 6 * C * C) return;
    int l = idx / (6 * C * C);
    int r0 = idx % (6 * C * C);
    int j = r0 & 7;
    int lane = (r0 >> 3) & 63;
    int rest = r0 >> 9;
    int tslot = rest % (3 * CT);
    int ks = rest / (3 * CT);
    int k = ks * 32 + (lane >> 4) * 8 + j;
    int g = tslot / CT;
    int lt = tslot % CT;
    int c = lt * 16 + (lane & 15);
    int row = g * C + c;
    float v = (k < C) ? Wc[((size_t)l * C + k) * 3 * C + row]
                      : whh[(size_t)row * C + (k - C)];
    unsigned short h = f2bf(v);
    BsHi[idx] = h;
    BsLo[idx] = f2bf(v - bf2f(h));
}

// ------------------------- gather: S[d] = sum X[src] ----------------------
// (identical to r15/r18)

template <int C>
__global__ __launch_bounds__(256) void gather_kernel(
    const unsigned short* __restrict__ Xhi,
    const int* __restrict__ rowstart, const int* __restrict__ csr_src,
    unsigned short* __restrict__ Shi, int N) {
    constexpr int LPG = C / 8;
    constexpr int GPB = 256 / LPG;
    int lane = threadIdx.x % LPG;
    int grp = threadIdx.x / LPG;
    int d = blockIdx.x * GPB + grp;
    if (d >= N) return;
    int p = rowstart[d];
    int p1 = rowstart[d + 1];
    float a[8];
#pragma unroll
    for (int j = 0; j < 8; ++j) a[j] = 0.f;
    int off = lane * 8;
    for (; p + 3 < p1; p += 4) {
        int s0 = csr_src[p];
        int s1 = csr_src[p + 1];
        int s2 = csr_src[p + 2];
        int s3 = csr_src[p + 3];
        u16x8 h0 = *(const u16x8*)(Xhi + (size_t)s0 * C + off);
        u16x8 h1 = *(const u16x8*)(Xhi + (size_t)s1 * C + off);
        u16x8 h2 = *(const u16x8*)(Xhi + (size_t)s2 * C + off);
        u16x8 h3 = *(const u16x8*)(Xhi + (size_t)s3 * C + off);
#pragma unroll
        for (int j = 0; j < 8; ++j) {
            a[j] += (bf2f(h0[j]) + bf2f(h1[j])) + (bf2f(h2[j]) + bf2f(h3[j]));
        }
    }
    for (; p < p1; ++p) {
        int s0 = csr_src[p];
        u16x8 h0 = *(const u16x8*)(Xhi + (size_t)s0 * C + off);
#pragma unroll
        for (int j = 0; j < 8; ++j) a[j] += bf2f(h0[j]);
    }
    size_t base = (size_t)d * C + off;
#pragma unroll
    for (int j = 0; j < 8; ++j) Shi[base + j] = f2bf(a[j]);
}

// ------------------------- GRU cell (C = 64 / 128) ------------------------
// Block = 4 waves = NT nodes (TPW = NT/16 A-tiles per wave). Wave w owns
// column tiles [w*CTW,(w+1)*CTW) of every gate. Out-of-place ping-pong.
// r24 split precision:
//   S-half (k<C):  A = Shi,      B = hi+lo -> 2 MFMA/acc (|S|-scaled term kept)
//   H-half (k>=C): A = Hin hi/lo, B = hi    -> 2 MFMA/acc (drops only ~0.002 term)

template <int C, int NT, int MINW>
__global__ __launch_bounds__(256, MINW) void gru_mfma_kernel(
    const unsigned short* __restrict__ HinHi, const unsigned short* __restrict__ HinLo,
    unsigned short* __restrict__ HoutHi, unsigned short* __restrict__ HoutLo,
    const unsigned short* __restrict__ Shi,
    const unsigned short* __restrict__ BsHi, const unsigned short* __restrict__ BsLo,
    const float* __restrict__ biasI, const float* __restrict__ biasH, int N) {
    constexpr int CT = C / 16;
    constexpr int KS = C / 16;  // 2C/32 k-steps
    constexpr int CTW = CT / 4;
    constexpr int TPW = NT / 16;  // node-tiles per wave
    int wave = threadIdx.x >> 6;
    int lane = threadIdx.x & 63;
    int quad = lane >> 4;
    int l16 = lane & 15;
    int node0 = blockIdx.x * NT;
    int arow[TPW];
#pragma unroll
    for (int t = 0; t < TPW; ++t) {
        int r = node0 + t * 16 + l16;
        arow[t] = r < N ? r : N - 1;
    }
    f32x4 accR[CTW][TPW], accZ[CTW][TPW], accN[CTW][TPW], accH[CTW][TPW];
#pragma unroll
    for (int ct = 0; ct < CTW; ++ct)
#pragma unroll
        for (int t = 0; t < TPW; ++t) {
            accR[ct][t] = (f32x4){0.f, 0.f, 0.f, 0.f};
            accZ[ct][t] = (f32x4){0.f, 0.f, 0.f, 0.f};
            accN[ct][t] = (f32x4){0.f, 0.f, 0.f, 0.f};
            accH[ct][t] = (f32x4){0.f, 0.f, 0.f, 0.f};
        }
    const short8* bhi = (const short8*)BsHi;
    const short8* blo = (const short8*)BsLo;

    // ---- S half (k < C): A = Shi, B = hi+lo (2 MFMA per acc) ----
    for (int ks = 0; ks < KS / 2; ++ks) {
        int k0 = ks * 32 + quad * 8;
        short8 ahi[TPW];
#pragma unroll
        for (int t = 0; t < TPW; ++t)
            ahi[t] = *(const short8*)(Shi + (size_t)arow[t] * C + k0);
#pragma unroll
        for (int ct = 0; ct < CTW; ++ct) {
            int ts = ks * 3 * CT + wave * CTW + ct;
            short8 bhf = bhi[(size_t)ts * 64 + lane];
            short8 blf = blo[(size_t)ts * 64 + lane];
#pragma unroll
            for (int t = 0; t < TPW; ++t) {
                accR[ct][t] = __builtin_amdgcn_mfma_f32_16x16x32_bf16(ahi[t], bhf, accR[ct][t], 0, 0, 0);
                accR[ct][t] = __builtin_amdgcn_mfma_f32_16x16x32_bf16(ahi[t], blf, accR[ct][t], 0, 0, 0);
            }
            bhf = bhi[(size_t)(ts + CT) * 64 + lane];
            blf = blo[(size_t)(ts + CT) * 64 + lane];
#pragma unroll
            for (int t = 0; t < TPW; ++t) {
                accZ[ct][t] = __builtin_amdgcn_mfma_f32_16x16x32_bf16(ahi[t], bhf, accZ[ct][t], 0, 0, 0);
                accZ[ct][t] = __builtin_amdgcn_mfma_f32_16x16x32_bf16(ahi[t], blf, accZ[ct][t], 0, 0, 0);
            }
            bhf = bhi[(size_t)(ts + 2 * CT) * 64 + lane];
            blf = blo[(size_t)(ts + 2 * CT) * 64 + lane];
#pragma unroll
            for (int t = 0; t < TPW; ++t) {
                accN[ct][t] = __builtin_amdgcn_mfma_f32_16x16x32_bf16(ahi[t], bhf, accN[ct][t], 0, 0, 0);
                accN[ct][t] = __builtin_amdgcn_mfma_f32_16x16x32_bf16(ahi[t], blf, accN[ct][t], 0, 0, 0);
            }
        }
    }
    // ---- H half (k >= C): A = Hin hi/lo, B = hi only (2 MFMA per acc) ----
    for (int ks = KS / 2; ks < KS; ++ks) {
        int k0 = ks * 32 + quad * 8 - C;
        short8 ahi[TPW], alo[TPW];
#pragma unroll
        for (int t = 0; t < TPW; ++t) {
            ahi[t] = *(const short8*)(HinHi + (size_t)arow[t] * C + k0);
            alo[t] = *(const short8*)(HinLo + (size_t)arow[t] * C + k0);
        }
#pragma unroll
        for (int ct = 0; ct < CTW; ++ct) {
            int ts = ks * 3 * CT + wave * CTW + ct;
            short8 bhf = bhi[(size_t)ts * 64 + lane];
#pragma unroll
            for (int t = 0; t < TPW; ++t) {
                accR[ct][t] = __builtin_amdgcn_mfma_f32_16x16x32_bf16(ahi[t], bhf, accR[ct][t], 0, 0, 0);
                accR[ct][t] = __builtin_amdgcn_mfma_f32_16x16x32_bf16(alo[t], bhf, accR[ct][t], 0, 0, 0);
            }
            bhf = bhi[(size_t)(ts + CT) * 64 + lane];
#pragma unroll
            for (int t = 0; t < TPW; ++t) {
                accZ[ct][t] = __builtin_amdgcn_mfma_f32_16x16x32_bf16(ahi[t], bhf, accZ[ct][t], 0, 0, 0);
                accZ[ct][t] = __builtin_amdgcn_mfma_f32_16x16x32_bf16(alo[t], bhf, accZ[ct][t], 0, 0, 0);
            }
            bhf = bhi[(size_t)(ts + 2 * CT) * 64 + lane];
#pragma unroll
            for (int t = 0; t < TPW; ++t) {
                accH[ct][t] = __builtin_amdgcn_mfma_f32_16x16x32_bf16(ahi[t], bhf, accH[ct][t], 0, 0, 0);
                accH[ct][t] = __builtin_amdgcn_mfma_f32_16x16x32_bf16(alo[t], bhf, accH[ct][t], 0, 0, 0);
            }
        }
    }

#pragma unroll
    for (int ct = 0; ct < CTW; ++ct) {
        int c = (wave * CTW + ct) * 16 + l16;
        float bir = biasI[c], biz = biasI[C + c], bin = biasI[2 * C + c];
        float bhr = biasH[c], bhz = biasH[C + c], bhn = biasH[2 * C + c];
#pragma unroll
        for (int t = 0; t < TPW; ++t) {
#pragma unroll
            for (int r = 0; r < 4; ++r) {
                int node = node0 + t * 16 + quad * 4 + r;
                if (node < N) {
                    size_t gi = (size_t)node * C + c;
                    float xo = bf2f(HinHi[gi]) + bf2f(HinLo[gi]);
                    float rv = sigmoid_f(accR[ct][t][r] + bir + bhr);
                    float zv = sigmoid_f(accZ[ct][t][r] + biz + bhz);
                    float nv = tanh_f(accN[ct][t][r] + bin + rv * (accH[ct][t][r] + bhn));
                    put_hl(HoutHi, HoutLo, gi, (1.f - zv) * nv + zv * xo);
                }
            }
        }
    }
}

// C=32 GRU: 1 A-tile per wave, out-of-place; r24 split precision
__global__ __launch_bounds__(256, 4) void gru32_kernel(
    const unsigned short* __restrict__ HinHi, const unsigned short* __restrict__ HinLo,
    unsigned short* __restrict__ HoutHi, unsigned short* __restrict__ HoutLo,
    const unsigned short* __restrict__ Shi,
    const unsigned short* __restrict__ BsHi, const unsigned short* __restrict__ BsLo,
    const float* __restrict__ biasI, const float* __restrict__ biasH, int N) {
    constexpr int C = 32;
    constexpr int CT = 2;
    int wave = threadIdx.x >> 6;
    int lane = threadIdx.x & 63;
    int quad = lane >> 4;
    int l16 = lane & 15;
    int node0 = blockIdx.x * 64 + wave * 16;
    int ar = node0 + l16;
    if (ar >= N) ar = N - 1;
    f32x4 accR[CT], accZ[CT], accN[CT], accH[CT];
#pragma unroll
    for (int t = 0; t < CT; ++t) {
        accR[t] = (f32x4){0.f, 0.f, 0.f, 0.f};
        accZ[t] = (f32x4){0.f, 0.f, 0.f, 0.f};
        accN[t] = (f32x4){0.f, 0.f, 0.f, 0.f};
        accH[t] = (f32x4){0.f, 0.f, 0.f, 0.f};
    }
    const short8* bhi = (const short8*)BsHi;
    const short8* blo = (const short8*)BsLo;
    int k0 = quad * 8;
    {  // ks = 0: S half (A=Shi, B hi+lo: 2 ops)
        short8 ahi = *(const short8*)(Shi + (size_t)ar * C + k0);
#pragma unroll
        for (int g = 0; g < 3; ++g) {
            f32x4* acc = g == 0 ? accR : (g == 1 ? accZ : accN);
#pragma unroll
            for (int t = 0; t < CT; ++t) {
                int ts = g * CT + t;
                short8 bhf = bhi[(size_t)ts * 64 + lane];
                short8 blf = blo[(size_t)ts * 64 + lane];
                acc[t] = __builtin_amdgcn_mfma_f32_16x16x32_bf16(ahi, bhf, acc[t], 0, 0, 0);
                acc[t] = __builtin_amdgcn_mfma_f32_16x16x32_bf16(ahi, blf, acc[t], 0, 0, 0);
            }
        }
    }
    {  // ks = 1: H half (A hi/lo, B hi only: 2 ops)
        short8 ahi = *(const short8*)(HinHi + (size_t)ar * C + k0);
        short8 alo = *(const short8*)(HinLo + (size_t)ar * C + k0);
#pragma unroll
        for (int g = 0; g < 3; ++g) {
            f32x4* acc = g == 0 ? accR : (g == 1 ? accZ : accH);
#pragma unroll
            for (int t = 0; t < CT; ++t) {
                int ts = 3 * CT + g * CT + t;
                short8 bhf = bhi[(size_t)ts * 64 + lane];
                acc[t] = __builtin_amdgcn_mfma_f32_16x16x32_bf16(ahi, bhf, acc[t], 0, 0, 0);
                acc[t] = __builtin_amdgcn_mfma_f32_16x16x32_bf16(alo, bhf, acc[t], 0, 0, 0);
            }
        }
    }
#pragma unroll
    for (int t = 0; t < CT; ++t) {
        int c = t * 16 + l16;
        float bir = biasI[c], biz = biasI[C + c], bin = biasI[2 * C + c];
        float bhr = biasH[c], bhz = biasH[C + c], bhn = biasH[2 * C + c];
#pragma unroll
        for (int r = 0; r < 4; ++r) {
            int node = node0 + quad * 4 + r;
            if (node < N) {
                size_t gi = (size_t)node * C + c;
                float xo = bf2f(HinHi[gi]) + bf2f(HinLo[gi]);
                float rv = sigmoid_f(accR[t][r] + bir + bhr);
                float zv = sigmoid_f(accZ[t][r] + biz + bhz);
                float nv = tanh_f(accN[t][r] + bin + rv * (accH[t][r] + bhn));
                put_hl(HoutHi, HoutLo, gi, (1.f - zv) * nv + zv * xo);
            }
        }
    }
}

// ------------------------- epilogues --------------------------------------

__global__ __launch_bounds__(256) void init_x_kernel(
    const float* __restrict__ x, unsigned short* __restrict__ Hhi,
    unsigned short* __restrict__ Hlo, int total) {
    int t = blockIdx.x * 256 + threadIdx.x;
    if (t < total) put_hl(Hhi, Hlo, t, x[t]);
}

template <int Cin, int Cout>
__global__ __launch_bounds__(256) void elu_bn_pad_kernel(
    const unsigned short* __restrict__ Shi, const unsigned short* __restrict__ Slo,
    unsigned short* __restrict__ Dhi, unsigned short* __restrict__ Dlo,
    const float* __restrict__ gamma, const float* __restrict__ beta,
    const float* __restrict__ mean, const float* __restrict__ var, int N) {
    long t = (long)blockIdx.x * 256 + threadIdx.x;
    long total = (long)N * Cout;
    if (t >= total) return;
    int n = (int)(t / Cout);
    int c = (int)(t & (Cout - 1));
    float v = 0.f;
    if (c < Cin) {
        size_t si = (size_t)n * Cin + c;
        float x = bf2f(Shi[si]) + bf2f(Slo[si]);
        x = elu_f(x);
        v = (x - mean[c]) * rsqrtf(var[c] + EPS_BN) * gamma[c] + beta[c];
    }
    put_hl(Dhi, Dlo, t, v);
}

__global__ __launch_bounds__(256) void pool_elu_kernel(
    const unsigned short* __restrict__ Hhi, const unsigned short* __restrict__ Hlo,
    const int* __restrict__ batch, float* __restrict__ G, int N) {
    long t = (long)blockIdx.x * 256 + threadIdx.x;
    if (t >= (long)N * 128) return;
    int n = (int)(t >> 7);
    int c = (int)(t & 127);
    float v = elu_f(bf2f(Hhi[t]) + bf2f(Hlo[t]));
    atomicAdd(&G[batch[n] * 128 + c], v);
}

__global__ __launch_bounds__(256) void fc1_kernel(
    const float* __restrict__ G, const float* __restrict__ W,
    const float* __restrict__ b, float* __restrict__ G2) {
    __shared__ float row[128];
    int g = blockIdx.x;
    int j = threadIdx.x;
    if (j < 128) row[j] = G[g * 128 + j];
    __syncthreads();
    float acc = b[j];
    for (int k = 0; k < 128; ++k) acc += row[k] * W[j * 128 + k];
    G2[g * 256 + j] = elu_f(acc);
}

__global__ __launch_bounds__(64) void fc2_logsoftmax_kernel(
    const float* __restrict__ G2, const float* __restrict__ W,
    const float* __restrict__ b, float* __restrict__ out) {
    __shared__ float row[256];
    __shared__ float logits[10];
    __shared__ float red[2];
    int g = blockIdx.x;
    int tid = threadIdx.x;
    for (int i = tid; i < 256; i += 64) row[i] = G2[g * 256 + i];
    __syncthreads();
    if (tid < 10) {
        float acc = b[tid];
        for (int k = 0; k < 256; ++k) acc += row[k] * W[tid * 256 + k];
        logits[tid] = acc;
    }
    __syncthreads();
    if (tid == 0) {
        float m = -1e30f;
        for (int a = 0; a < 10; ++a) m = fmaxf(m, logits[a]);
        float s = 0.f;
        for (int a = 0; a < 10; ++a) s += expf(logits[a] - m);
        red[0] = m;
        red[1] = logf(s);
    }
    __syncthreads();
    if (tid < 10) out[g * 10 + tid] = logits[tid] - red[0] - red[1];
}

// ---------------------------------------------------------------------------

template <int C>
static void run_conv(unsigned short* Ahi, unsigned short* Alo,
                     unsigned short* Bhi, unsigned short* Blo,
                     unsigned short* Shi,
                     float* Wc, unsigned short* BsHi, unsigned short* BsLo,
                     const float* W, const float* wih, const float* whh,
                     const float* bih, const float* bhh,
                     const int* rowstart, const int* csr_src,
                     int N, int E, hipStream_t stream) {
    wc_kernel<C><<<(4 * C * 3 * C + 255) / 256, 256, 0, stream>>>(W, wih, Wc);
    swizzle_b2_kernel<C><<<(4 * 6 * C * C + 255) / 256, 256, 0, stream>>>(Wc, whh, BsHi, BsLo);
    constexpr int NT = (C == 128) ? 32 : 64;  // nodes per GRU block
    int nb = (N + NT - 1) / NT;
    constexpr int GPB = 2048 / C;  // gather dst-groups per block (C/8 lanes)
    int gblocks = (N + GPB - 1) / GPB;
    unsigned short *inHi = Ahi, *inLo = Alo, *outHi = Bhi, *outLo = Blo;
    for (int it = 0; it < 4; ++it) {
        gather_kernel<C><<<gblocks, 256, 0, stream>>>(
            inHi, rowstart, csr_src, Shi, N);
        const unsigned short* bs_h = BsHi + (size_t)it * 6 * C * C;
        const unsigned short* bs_l = BsLo + (size_t)it * 6 * C * C;
        if constexpr (C == 32)
            gru32_kernel<<<nb, 256, 0, stream>>>(
                inHi, inLo, outHi, outLo, Shi, bs_h, bs_l, bih, bhh, N);
        else
            gru_mfma_kernel<C, NT, 3><<<nb, 256, 0, stream>>>(
                inHi, inLo, outHi, outLo, Shi, bs_h, bs_l, bih, bhh, N);
        unsigned short* tp;
        tp = inHi; inHi = outHi; outHi = tp;
        tp = inLo; inLo = outLo; outLo = tp;
    }
    // 4 iterations (even) -> final state back in (Ahi, Alo)
}

extern "C" void kernel_launch(void* const* d_in, const int* in_sizes, int n_in,
                              void* d_out, int out_size, void* d_ws, size_t ws_size,
                              hipStream_t stream) {
    const float* x = (const float*)d_in[0];
    const int* ei = (const int*)d_in[1];
    const int* batch = (const int*)d_in[2];
    const float* fc1W = (const float*)d_in[3];
    const float* fc1b = (const float*)d_in[4];
    const float* fc2W = (const float*)d_in[5];
    const float* fc2b = (const float*)d_in[6];
    const float* c1W = (const float*)d_in[7];
    const float* c1wih = (const float*)d_in[8];
    const float* c1whh = (const float*)d_in[9];
    const float* c1bih = (const float*)d_in[10];
    const float* c1bhh = (const float*)d_in[11];
    const float* c2W = (const float*)d_in[12];
    const float* c2wih = (const float*)d_in[13];
    const float* c2whh = (const float*)d_in[14];
    const float* c2bih = (const float*)d_in[15];
    const float* c2bhh = (const float*)d_in[16];
    const float* c3W = (const float*)d_in[17];
    const float* c3wih = (const float*)d_in[18];
    const float* c3whh = (const float*)d_in[19];
    const float* c3bih = (const float*)d_in[20];
    const float* c3bhh = (const float*)d_in[21];
    const float* bn1g = (const float*)d_in[22];
    const float* bn1b = (const float*)d_in[23];
    const float* bn1m = (const float*)d_in[24];
    const float* bn1v = (const float*)d_in[25];
    const float* bn2g = (const float*)d_in[26];
    const float* bn2b = (const float*)d_in[27];
    const float* bn2m = (const float*)d_in[28];
    const float* bn2v = (const float*)d_in[29];

    int N = in_sizes[0] / 32;
    int E = in_sizes[1] / 2;

    const size_t NB = (size_t)N * 128;  // shorts per plane
    unsigned short* PAhi = (unsigned short*)d_ws;  // state pair A
    unsigned short* PAlo = PAhi + NB;
    unsigned short* PBhi = PAlo + NB;              // state pair B (ping-pong)
    unsigned short* PBlo = PBhi + NB;
    unsigned short* Shi = PBlo + NB;               // gathered-S (hi-only)
    unsigned short* Slo = Shi + NB;                // (unused; kept for layout)
    unsigned short* BsHi = Slo + NB;               // 4 layers x 6*C*C <= 393216
    unsigned short* BsLo = BsHi + 393216;
    float* Wc = (float*)(BsLo + 393216);           // 4*C*3C <= 196608 floats
    float* G = Wc + 196608;
    float* G2 = G + 32768;
    int* deg = (int*)(G2 + 65536);
    int* scanout = deg + N;
    int* rowstart = scanout + N;
    int* writeptr = rowstart + N + 1;
    int* blockSums = writeptr + N;
    int* csr_src = blockSums + 64;

    // ---- build CSR by dst (once; reused by all 12 propagation steps) ----
    hipMemsetAsync(deg, 0, (size_t)N * sizeof(int), stream);
    int eblocks = (E + 255) / 256;
    hist_kernel<<<eblocks, 256, 0, stream>>>(ei, deg, E);
    int nscan = (N + 1023) / 1024;
    scan1_kernel<<<nscan, 256, 0, stream>>>(deg, scanout, blockSums, N);
    scan2_kernel<<<1, 64, 0, stream>>>(blockSums, nscan);
    scan3_kernel<<<(N + 255) / 256, 256, 0, stream>>>(scanout, blockSums, rowstart, writeptr, N, E);
    fill_kernel<<<eblocks, 256, 0, stream>>>(ei, writeptr, csr_src, E);

    // x -> pair A hi/lo ([N,32])
    init_x_kernel<<<(N * 32 + 255) / 256, 256, 0, stream>>>(x, PAhi, PAlo, N * 32);

    // conv1 (C=32): state PA, ping-pong with PB
    run_conv<32>(PAhi, PAlo, PBhi, PBlo, Shi, Wc, BsHi, BsLo,
                 c1W, c1wih, c1whh, c1bih, c1bhh, rowstart, csr_src, N, E, stream);
    elu_bn_pad_kernel<32, 64><<<(int)(((long)N * 64 + 255) / 256), 256, 0, stream>>>(
        PAhi, PAlo, PBhi, PBlo, bn1g, bn1b, bn1m, bn1v, N);

    // conv2 (C=64): state PB, ping-pong with PA
    run_conv<64>(PBhi, PBlo, PAhi, PAlo, Shi, Wc, BsHi, BsLo,
                 c2W, c2wih, c2whh, c2bih, c2bhh, rowstart, csr_src, N, E, stream);
    elu_bn_pad_kernel<64, 128><<<(int)(((long)N * 128 + 255) / 256), 256, 0, stream>>>(
        PBhi, PBlo, PAhi, PAlo, bn2g, bn2b, bn2m, bn2v, N);

    // conv3 (C=128): state PA, ping-pong with PB
    run_conv<128>(PAhi, PAlo, PBhi, PBlo, Shi, Wc, BsHi, BsLo,
                  c3W, c3wih, c3whh, c3bih, c3bhh, rowstart, csr_src, N, E, stream);

    // pool (reads pair A, stride 128)
    hipMemsetAsync(G, 0, 256 * 128 * sizeof(float), stream);
    pool_elu_kernel<<<(int)(((long)N * 128 + 255) / 256), 256, 0, stream>>>(
        PAhi, PAlo, batch, G, N);

    fc1_kernel<<<256, 256, 0, stream>>>(G, fc1W, fc1b, G2);
    fc2_logsoftmax_kernel<<<256, 64, 0, stream>>>(G2, fc2W, fc2b, (float*)d_out);
}

// Round 10
// 846.607 us; speedup vs baseline: 3.1892x; 1.0193x over previous
//
#include <hip/hip_runtime.h>
#include <math.h>

// ---------------------------------------------------------------------------
// GNN: 3x GatedGraphConv (C=32,64,128; 4 inner layers each) + BN + pool + MLP
// Round 25: r24 (split-precision B, 863 us) + XCD-partitioned CSR build.
// fill_kernel wrote 53 MB HBM (16x amplification) for a 3.2 MB csr_src:
// random 4B scatters from all 8 XCDs ping-pong 64B lines between
// non-coherent L2s, each bounce = HBM writeback. Fix: 8 dst-range
// partitions, blocks with bid&7==p handle range p (default round-robin
// block->XCD mapping heuristic; atomics stay device-scope so correctness
// never depends on it). Range slices (~400KB) stay L2-resident -> writes
// merge. Cost: 8x dst re-read (L3-absorbed). Same for hist_kernel.
// ---------------------------------------------------------------------------

#define EPS_BN 1e-5f

typedef short short8 __attribute__((ext_vector_type(8)));
typedef unsigned short u16x8 __attribute__((ext_vector_type(8)));
typedef float f32x4 __attribute__((ext_vector_type(4)));

__device__ __forceinline__ float elu_f(float v) {
    return v > 0.f ? v : expm1f(v);
}
__device__ __forceinline__ float sigmoid_f(float v) {
    return 1.f / (1.f + __expf(-v));
}
__device__ __forceinline__ float tanh_f(float v) {
    float e = __expf(2.f * v);
    return 1.f - 2.f / (e + 1.f);
}
__device__ __forceinline__ unsigned short f2bf(float f) {
    unsigned u = __float_as_uint(f);
    unsigned r = (u + 0x7FFF + ((u >> 16) & 1)) >> 16;
    return (unsigned short)r;
}
__device__ __forceinline__ float bf2f(unsigned short b) {
    return __uint_as_float(((unsigned)b) << 16);
}
__device__ __forceinline__ void put_hl(unsigned short* __restrict__ hi,
                                       unsigned short* __restrict__ lo,
                                       size_t idx, float v) {
    unsigned short h = f2bf(v);
    hi[idx] = h;
    lo[idx] = f2bf(v - bf2f(h));
}

// ------------------------- CSR construction -------------------------------
// hist/fill: dst-range partitioned over 8 XCD-heuristic groups (r25).

__global__ __launch_bounds__(256) void hist_kernel(
    const int* __restrict__ ei, int* __restrict__ deg, int E, int N) {
    int part = blockIdx.x & 7;
    int blk = blockIdx.x >> 3;
    int nblk = gridDim.x >> 3;
    int lo = (int)((long)N * part >> 3);
    int hi = (int)((long)N * (part + 1) >> 3);
    for (int e = blk * 256 + threadIdx.x; e < E; e += nblk * 256) {
        int d = ei[E + e];
        if (d >= lo && d < hi) atomicAdd(&deg[d], 1);
    }
}

__global__ __launch_bounds__(256) void scan1_kernel(
    const int* __restrict__ deg, int* __restrict__ out,
    int* __restrict__ blockSums, int N) {
    __shared__ int sdata[256];
    int b = blockIdx.x, t = threadIdx.x;
    int base = b * 1024 + t * 4;
    int v[4], s = 0;
#pragma unroll
    for (int i = 0; i < 4; ++i) {
        v[i] = (base + i < N) ? deg[base + i] : 0;
        s += v[i];
    }
    sdata[t] = s;
    __syncthreads();
    for (int off = 1; off < 256; off <<= 1) {
        int x = (t >= off) ? sdata[t - off] : 0;
        __syncthreads();
        sdata[t] += x;
        __syncthreads();
    }
    int run = sdata[t] - s;
#pragma unroll
    for (int i = 0; i < 4; ++i) {
        if (base + i < N) out[base + i] = run;
        run += v[i];
    }
    if (t == 255) blockSums[b] = sdata[255];
}

__global__ void scan2_kernel(int* blockSums, int nb) {
    if (threadIdx.x == 0 && blockIdx.x == 0) {
        int run = 0;
        for (int i = 0; i < nb; ++i) {
            int v = blockSums[i];
            blockSums[i] = run;
            run += v;
        }
    }
}

__global__ __launch_bounds__(256) void scan3_kernel(
    const int* __restrict__ out, const int* __restrict__ blockSums,
    int* __restrict__ rowstart, int* __restrict__ writeptr, int N, int E) {
    int i = blockIdx.x * 256 + threadIdx.x;
    if (i < N) {
        int v = out[i] + blockSums[i >> 10];
        rowstart[i] = v;
        writeptr[i] = v;
    }
    if (i == 0) rowstart[N] = E;
}

__global__ __launch_bounds__(256) void fill_kernel(
    const int* __restrict__ ei, int* __restrict__ writeptr,
    int* __restrict__ csr_src, int E, int N) {
    int part = blockIdx.x & 7;
    int blk = blockIdx.x >> 3;
    int nblk = gridDim.x >> 3;
    int lo = (int)((long)N * part >> 3);
    int hi = (int)((long)N * (part + 1) >> 3);
    for (int e = blk * 256 + threadIdx.x; e < E; e += nblk * 256) {
        int d = ei[E + e];
        if (d >= lo && d < hi) {
            int p = atomicAdd(&writeptr[d], 1);
            csr_src[p] = ei[e];
        }
    }
}

// ------------------------- Wc = W[l] @ wih^T ------------------------------

template <int C>
__global__ __launch_bounds__(256) void wc_kernel(
    const float* __restrict__ W, const float* __restrict__ wih,
    float* __restrict__ Wc) {
    int idx = blockIdx.x * 256 + threadIdx.x;
    if (idx >= 4 * C * 3 * C) return;
    int l = idx / (C * 3 * C);
    int r = idx % (C * 3 * C);
    int k = r / (3 * C);
    int row = r % (3 * C);
    const float* wrow = W + ((size_t)l * C + k) * C;
    const float* irow = wih + (size_t)row * C;
    float acc = 0.f;
#pragma unroll 4
    for (int t = 0; t < C; ++t) acc += wrow[t] * irow[t];
    Wc[idx] = acc;
}

// ------------------------- B2 swizzle (hi/lo, all 4 layers) ---------------
// mfma_f32_16x16x32_bf16:
//   A[m][k]: m = lane&15, k = (lane>>4)*8 + j
//   B[k][n]: n = lane&15, k = (lane>>4)*8 + j
//   C/D:     col = lane&15, row = (lane>>4)*4 + reg
// GRU concat-B: K = 2C (k<C: Wc_l on S; k>=C: whh on H).
// tslot per ks: [0,CT): r ; [CT,2CT): z ; [2CT,3CT): k<C ? in : hn
// BsLo only consumed for k<C (S-half) since r24.

template <int C>
__global__ __launch_bounds__(256) void swizzle_b2_kernel(
    const float* __restrict__ Wc, const float* __restrict__ whh,
    unsigned short* __restrict__ BsHi, unsigned short* __restrict__ BsLo) {
    constexpr int CT = C / 16;
    int idx = blockIdx.x * 256 + threadIdx.x;
    if (idx >= 4 * 6 * C * C) return;
    int l = idx / (6 * C * C);
    int r0 = idx % (6 * C * C);
    int j = r0 & 7;
    int lane = (r0 >> 3) & 63;
    int rest = r0 >> 9;
    int tslot = rest % (3 * CT);
    int ks = rest / (3 * CT);
    int k = ks * 32 + (lane >> 4) * 8 + j;
    int g = tslot / CT;
    int lt = tslot % CT;
    int c = lt * 16 + (lane & 15);
    int row = g * C + c;
    float v = (k < C) ? Wc[((size_t)l * C + k) * 3 * C + row]
                      : whh[(size_t)row * C + (k - C)];
    unsigned short h = f2bf(v);
    BsHi[idx] = h;
    BsLo[idx] = f2bf(v - bf2f(h));
}

// ------------------------- gather: S[d] = sum X[src] ----------------------
// (identical to r15/r18)

template <int C>
__global__ __launch_bounds__(256) void gather_kernel(
    const unsigned short* __restrict__ Xhi,
    const int* __restrict__ rowstart, const int* __restrict__ csr_src,
    unsigned short* __restrict__ Shi, int N) {
    constexpr int LPG = C / 8;
    constexpr int GPB = 256 / LPG;
    int lane = threadIdx.x % LPG;
    int grp = threadIdx.x / LPG;
    int d = blockIdx.x * GPB + grp;
    if (d >= N) return;
    int p = rowstart[d];
    int p1 = rowstart[d + 1];
    float a[8];
#pragma unroll
    for (int j = 0; j < 8; ++j) a[j] = 0.f;
    int off = lane * 8;
    for (; p + 3 < p1; p += 4) {
        int s0 = csr_src[p];
        int s1 = csr_src[p + 1];
        int s2 = csr_src[p + 2];
        int s3 = csr_src[p + 3];
        u16x8 h0 = *(const u16x8*)(Xhi + (size_t)s0 * C + off);
        u16x8 h1 = *(const u16x8*)(Xhi + (size_t)s1 * C + off);
        u16x8 h2 = *(const u16x8*)(Xhi + (size_t)s2 * C + off);
        u16x8 h3 = *(const u16x8*)(Xhi + (size_t)s3 * C + off);
#pragma unroll
        for (int j = 0; j < 8; ++j) {
            a[j] += (bf2f(h0[j]) + bf2f(h1[j])) + (bf2f(h2[j]) + bf2f(h3[j]));
        }
    }
    for (; p < p1; ++p) {
        int s0 = csr_src[p];
        u16x8 h0 = *(const u16x8*)(Xhi + (size_t)s0 * C + off);
#pragma unroll
        for (int j = 0; j < 8; ++j) a[j] += bf2f(h0[j]);
    }
    size_t base = (size_t)d * C + off;
#pragma unroll
    for (int j = 0; j < 8; ++j) Shi[base + j] = f2bf(a[j]);
}

// ------------------------- GRU cell (C = 64 / 128) ------------------------
// Block = 4 waves = NT nodes (TPW = NT/16 A-tiles per wave). Wave w owns
// column tiles [w*CTW,(w+1)*CTW) of every gate. Out-of-place ping-pong.
// r24 split precision:
//   S-half (k<C):  A = Shi,      B = hi+lo -> 2 MFMA/acc (|S|-scaled term kept)
//   H-half (k>=C): A = Hin hi/lo, B = hi    -> 2 MFMA/acc (drops only ~0.002 term)

template <int C, int NT, int MINW>
__global__ __launch_bounds__(256, MINW) void gru_mfma_kernel(
    const unsigned short* __restrict__ HinHi, const unsigned short* __restrict__ HinLo,
    unsigned short* __restrict__ HoutHi, unsigned short* __restrict__ HoutLo,
    const unsigned short* __restrict__ Shi,
    const unsigned short* __restrict__ BsHi, const unsigned short* __restrict__ BsLo,
    const float* __restrict__ biasI, const float* __restrict__ biasH, int N) {
    constexpr int CT = C / 16;
    constexpr int KS = C / 16;  // 2C/32 k-steps
    constexpr int CTW = CT / 4;
    constexpr int TPW = NT / 16;  // node-tiles per wave
    int wave = threadIdx.x >> 6;
    int lane = threadIdx.x & 63;
    int quad = lane >> 4;
    int l16 = lane & 15;
    int node0 = blockIdx.x * NT;
    int arow[TPW];
#pragma unroll
    for (int t = 0; t < TPW; ++t) {
        int r = node0 + t * 16 + l16;
        arow[t] = r < N ? r : N - 1;
    }
    f32x4 accR[CTW][TPW], accZ[CTW][TPW], accN[CTW][TPW], accH[CTW][TPW];
#pragma unroll
    for (int ct = 0; ct < CTW; ++ct)
#pragma unroll
        for (int t = 0; t < TPW; ++t) {
            accR[ct][t] = (f32x4){0.f, 0.f, 0.f, 0.f};
            accZ[ct][t] = (f32x4){0.f, 0.f, 0.f, 0.f};
            accN[ct][t] = (f32x4){0.f, 0.f, 0.f, 0.f};
            accH[ct][t] = (f32x4){0.f, 0.f, 0.f, 0.f};
        }
    const short8* bhi = (const short8*)BsHi;
    const short8* blo = (const short8*)BsLo;

    // ---- S half (k < C): A = Shi, B = hi+lo (2 MFMA per acc) ----
    for (int ks = 0; ks < KS / 2; ++ks) {
        int k0 = ks * 32 + quad * 8;
        short8 ahi[TPW];
#pragma unroll
        for (int t = 0; t < TPW; ++t)
            ahi[t] = *(const short8*)(Shi + (size_t)arow[t] * C + k0);
#pragma unroll
        for (int ct = 0; ct < CTW; ++ct) {
            int ts = ks * 3 * CT + wave * CTW + ct;
            short8 bhf = bhi[(size_t)ts * 64 + lane];
            short8 blf = blo[(size_t)ts * 64 + lane];
#pragma unroll
            for (int t = 0; t < TPW; ++t) {
                accR[ct][t] = __builtin_amdgcn_mfma_f32_16x16x32_bf16(ahi[t], bhf, accR[ct][t], 0, 0, 0);
                accR[ct][t] = __builtin_amdgcn_mfma_f32_16x16x32_bf16(ahi[t], blf, accR[ct][t], 0, 0, 0);
            }
            bhf = bhi[(size_t)(ts + CT) * 64 + lane];
            blf = blo[(size_t)(ts + CT) * 64 + lane];
#pragma unroll
            for (int t = 0; t < TPW; ++t) {
                accZ[ct][t] = __builtin_amdgcn_mfma_f32_16x16x32_bf16(ahi[t], bhf, accZ[ct][t], 0, 0, 0);
                accZ[ct][t] = __builtin_amdgcn_mfma_f32_16x16x32_bf16(ahi[t], blf, accZ[ct][t], 0, 0, 0);
            }
            bhf = bhi[(size_t)(ts + 2 * CT) * 64 + lane];
            blf = blo[(size_t)(ts + 2 * CT) * 64 + lane];
#pragma unroll
            for (int t = 0; t < TPW; ++t) {
                accN[ct][t] = __builtin_amdgcn_mfma_f32_16x16x32_bf16(ahi[t], bhf, accN[ct][t], 0, 0, 0);
                accN[ct][t] = __builtin_amdgcn_mfma_f32_16x16x32_bf16(ahi[t], blf, accN[ct][t], 0, 0, 0);
            }
        }
    }
    // ---- H half (k >= C): A = Hin hi/lo, B = hi only (2 MFMA per acc) ----
    for (int ks = KS / 2; ks < KS; ++ks) {
        int k0 = ks * 32 + quad * 8 - C;
        short8 ahi[TPW], alo[TPW];
#pragma unroll
        for (int t = 0; t < TPW; ++t) {
            ahi[t] = *(const short8*)(HinHi + (size_t)arow[t] * C + k0);
            alo[t] = *(const short8*)(HinLo + (size_t)arow[t] * C + k0);
        }
#pragma unroll
        for (int ct = 0; ct < CTW; ++ct) {
            int ts = ks * 3 * CT + wave * CTW + ct;
            short8 bhf = bhi[(size_t)ts * 64 + lane];
#pragma unroll
            for (int t = 0; t < TPW; ++t) {
                accR[ct][t] = __builtin_amdgcn_mfma_f32_16x16x32_bf16(ahi[t], bhf, accR[ct][t], 0, 0, 0);
                accR[ct][t] = __builtin_amdgcn_mfma_f32_16x16x32_bf16(alo[t], bhf, accR[ct][t], 0, 0, 0);
            }
            bhf = bhi[(size_t)(ts + CT) * 64 + lane];
#pragma unroll
            for (int t = 0; t < TPW; ++t) {
                accZ[ct][t] = __builtin_amdgcn_mfma_f32_16x16x32_bf16(ahi[t], bhf, accZ[ct][t], 0, 0, 0);
                accZ[ct][t] = __builtin_amdgcn_mfma_f32_16x16x32_bf16(alo[t], bhf, accZ[ct][t], 0, 0, 0);
            }
            bhf = bhi[(size_t)(ts + 2 * CT) * 64 + lane];
#pragma unroll
            for (int t = 0; t < TPW; ++t) {
                accH[ct][t] = __builtin_amdgcn_mfma_f32_16x16x32_bf16(ahi[t], bhf, accH[ct][t], 0, 0, 0);
                accH[ct][t] = __builtin_amdgcn_mfma_f32_16x16x32_bf16(alo[t], bhf, accH[ct][t], 0, 0, 0);
            }
        }
    }

#pragma unroll
    for (int ct = 0; ct < CTW; ++ct) {
        int c = (wave * CTW + ct) * 16 + l16;
        float bir = biasI[c], biz = biasI[C + c], bin = biasI[2 * C + c];
        float bhr = biasH[c], bhz = biasH[C + c], bhn = biasH[2 * C + c];
#pragma unroll
        for (int t = 0; t < TPW; ++t) {
#pragma unroll
            for (int r = 0; r < 4; ++r) {
                int node = node0 + t * 16 + quad * 4 + r;
                if (node < N) {
                    size_t gi = (size_t)node * C + c;
                    float xo = bf2f(HinHi[gi]) + bf2f(HinLo[gi]);
                    float rv = sigmoid_f(accR[ct][t][r] + bir + bhr);
                    float zv = sigmoid_f(accZ[ct][t][r] + biz + bhz);
                    float nv = tanh_f(accN[ct][t][r] + bin + rv * (accH[ct][t][r] + bhn));
                    put_hl(HoutHi, HoutLo, gi, (1.f - zv) * nv + zv * xo);
                }
            }
        }
    }
}

// C=32 GRU: 1 A-tile per wave, out-of-place; r24 split precision
__global__ __launch_bounds__(256, 4) void gru32_kernel(
    const unsigned short* __restrict__ HinHi, const unsigned short* __restrict__ HinLo,
    unsigned short* __restrict__ HoutHi, unsigned short* __restrict__ HoutLo,
    const unsigned short* __restrict__ Shi,
    const unsigned short* __restrict__ BsHi, const unsigned short* __restrict__ BsLo,
    const float* __restrict__ biasI, const float* __restrict__ biasH, int N) {
    constexpr int C = 32;
    constexpr int CT = 2;
    int wave = threadIdx.x >> 6;
    int lane = threadIdx.x & 63;
    int quad = lane >> 4;
    int l16 = lane & 15;
    int node0 = blockIdx.x * 64 + wave * 16;
    int ar = node0 + l16;
    if (ar >= N) ar = N - 1;
    f32x4 accR[CT], accZ[CT], accN[CT], accH[CT];
#pragma unroll
    for (int t = 0; t < CT; ++t) {
        accR[t] = (f32x4){0.f, 0.f, 0.f, 0.f};
        accZ[t] = (f32x4){0.f, 0.f, 0.f, 0.f};
        accN[t] = (f32x4){0.f, 0.f, 0.f, 0.f};
        accH[t] = (f32x4){0.f, 0.f, 0.f, 0.f};
    }
    const short8* bhi = (const short8*)BsHi;
    const short8* blo = (const short8*)BsLo;
    int k0 = quad * 8;
    {  // ks = 0: S half (A=Shi, B hi+lo: 2 ops)
        short8 ahi = *(const short8*)(Shi + (size_t)ar * C + k0);
#pragma unroll
        for (int g = 0; g < 3; ++g) {
            f32x4* acc = g == 0 ? accR : (g == 1 ? accZ : accN);
#pragma unroll
            for (int t = 0; t < CT; ++t) {
                int ts = g * CT + t;
                short8 bhf = bhi[(size_t)ts * 64 + lane];
                short8 blf = blo[(size_t)ts * 64 + lane];
                acc[t] = __builtin_amdgcn_mfma_f32_16x16x32_bf16(ahi, bhf, acc[t], 0, 0, 0);
                acc[t] = __builtin_amdgcn_mfma_f32_16x16x32_bf16(ahi, blf, acc[t], 0, 0, 0);
            }
        }
    }
    {  // ks = 1: H half (A hi/lo, B hi only: 2 ops)
        short8 ahi = *(const short8*)(HinHi + (size_t)ar * C + k0);
        short8 alo = *(const short8*)(HinLo + (size_t)ar * C + k0);
#pragma unroll
        for (int g = 0; g < 3; ++g) {
            f32x4* acc = g == 0 ? accR : (g == 1 ? accZ : accH);
#pragma unroll
            for (int t = 0; t < CT; ++t) {
                int ts = 3 * CT + g * CT + t;
                short8 bhf = bhi[(size_t)ts * 64 + lane];
                acc[t] = __builtin_amdgcn_mfma_f32_16x16x32_bf16(ahi, bhf, acc[t], 0, 0, 0);
                acc[t] = __builtin_amdgcn_mfma_f32_16x16x32_bf16(alo, bhf, acc[t], 0, 0, 0);
            }
        }
    }
#pragma unroll
    for (int t = 0; t < CT; ++t) {
        int c = t * 16 + l16;
        float bir = biasI[c], biz = biasI[C + c], bin = biasI[2 * C + c];
        float bhr = biasH[c], bhz = biasH[C + c], bhn = biasH[2 * C + c];
#pragma unroll
        for (int r = 0; r < 4; ++r) {
            int node = node0 + quad * 4 + r;
            if (node < N) {
                size_t gi = (size_t)node * C + c;
                float xo = bf2f(HinHi[gi]) + bf2f(HinLo[gi]);
                float rv = sigmoid_f(accR[t][r] + bir + bhr);
                float zv = sigmoid_f(accZ[t][r] + biz + bhz);
                float nv = tanh_f(accN[t][r] + bin + rv * (accH[t][r] + bhn));
                put_hl(HoutHi, HoutLo, gi, (1.f - zv) * nv + zv * xo);
            }
        }
    }
}

// ------------------------- epilogues --------------------------------------

__global__ __launch_bounds__(256) void init_x_kernel(
    const float* __restrict__ x, unsigned short* __restrict__ Hhi,
    unsigned short* __restrict__ Hlo, int total) {
    int t = blockIdx.x * 256 + threadIdx.x;
    if (t < total) put_hl(Hhi, Hlo, t, x[t]);
}

template <int Cin, int Cout>
__global__ __launch_bounds__(256) void elu_bn_pad_kernel(
    const unsigned short* __restrict__ Shi, const unsigned short* __restrict__ Slo,
    unsigned short* __restrict__ Dhi, unsigned short* __restrict__ Dlo,
    const float* __restrict__ gamma, const float* __restrict__ beta,
    const float* __restrict__ mean, const float* __restrict__ var, int N) {
    long t = (long)blockIdx.x * 256 + threadIdx.x;
    long total = (long)N * Cout;
    if (t >= total) return;
    int n = (int)(t / Cout);
    int c = (int)(t & (Cout - 1));
    float v = 0.f;
    if (c < Cin) {
        size_t si = (size_t)n * Cin + c;
        float x = bf2f(Shi[si]) + bf2f(Slo[si]);
        x = elu_f(x);
        v = (x - mean[c]) * rsqrtf(var[c] + EPS_BN) * gamma[c] + beta[c];
    }
    put_hl(Dhi, Dlo, t, v);
}

__global__ __launch_bounds__(256) void pool_elu_kernel(
    const unsigned short* __restrict__ Hhi, const unsigned short* __restrict__ Hlo,
    const int* __restrict__ batch, float* __restrict__ G, int N) {
    long t = (long)blockIdx.x * 256 + threadIdx.x;
    if (t >= (long)N * 128) return;
    int n = (int)(t >> 7);
    int c = (int)(t & 127);
    float v = elu_f(bf2f(Hhi[t]) + bf2f(Hlo[t]));
    atomicAdd(&G[batch[n] * 128 + c], v);
}

__global__ __launch_bounds__(256) void fc1_kernel(
    const float* __restrict__ G, const float* __restrict__ W,
    const float* __restrict__ b, float* __restrict__ G2) {
    __shared__ float row[128];
    int g = blockIdx.x;
    int j = threadIdx.x;
    if (j < 128) row[j] = G[g * 128 + j];
    __syncthreads();
    float acc = b[j];
    for (int k = 0; k < 128; ++k) acc += row[k] * W[j * 128 + k];
    G2[g * 256 + j] = elu_f(acc);
}

__global__ __launch_bounds__(64) void fc2_logsoftmax_kernel(
    const float* __restrict__ G2, const float* __restrict__ W,
    const float* __restrict__ b, float* __restrict__ out) {
    __shared__ float row[256];
    __shared__ float logits[10];
    __shared__ float red[2];
    int g = blockIdx.x;
    int tid = threadIdx.x;
    for (int i = tid; i < 256; i += 64) row[i] = G2[g * 256 + i];
    __syncthreads();
    if (tid < 10) {
        float acc = b[tid];
        for (int k = 0; k < 256; ++k) acc += row[k] * W[tid * 256 + k];
        logits[tid] = acc;
    }
    __syncthreads();
    if (tid == 0) {
        float m = -1e30f;
        for (int a = 0; a < 10; ++a) m = fmaxf(m, logits[a]);
        float s = 0.f;
        for (int a = 0; a < 10; ++a) s += expf(logits[a] - m);
        red[0] = m;
        red[1] = logf(s);
    }
    __syncthreads();
    if (tid < 10) out[g * 10 + tid] = logits[tid] - red[0] - red[1];
}

// ---------------------------------------------------------------------------

template <int C>
static void run_conv(unsigned short* Ahi, unsigned short* Alo,
                     unsigned short* Bhi, unsigned short* Blo,
                     unsigned short* Shi,
                     float* Wc, unsigned short* BsHi, unsigned short* BsLo,
                     const float* W, const float* wih, const float* whh,
                     const float* bih, const float* bhh,
                     const int* rowstart, const int* csr_src,
                     int N, int E, hipStream_t stream) {
    wc_kernel<C><<<(4 * C * 3 * C + 255) / 256, 256, 0, stream>>>(W, wih, Wc);
    swizzle_b2_kernel<C><<<(4 * 6 * C * C + 255) / 256, 256, 0, stream>>>(Wc, whh, BsHi, BsLo);
    constexpr int NT = (C == 128) ? 32 : 64;  // nodes per GRU block
    int nb = (N + NT - 1) / NT;
    constexpr int GPB = 2048 / C;  // gather dst-groups per block (C/8 lanes)
    int gblocks = (N + GPB - 1) / GPB;
    unsigned short *inHi = Ahi, *inLo = Alo, *outHi = Bhi, *outLo = Blo;
    for (int it = 0; it < 4; ++it) {
        gather_kernel<C><<<gblocks, 256, 0, stream>>>(
            inHi, rowstart, csr_src, Shi, N);
        const unsigned short* bs_h = BsHi + (size_t)it * 6 * C * C;
        const unsigned short* bs_l = BsLo + (size_t)it * 6 * C * C;
        if constexpr (C == 32)
            gru32_kernel<<<nb, 256, 0, stream>>>(
                inHi, inLo, outHi, outLo, Shi, bs_h, bs_l, bih, bhh, N);
        else
            gru_mfma_kernel<C, NT, 3><<<nb, 256, 0, stream>>>(
                inHi, inLo, outHi, outLo, Shi, bs_h, bs_l, bih, bhh, N);
        unsigned short* tp;
        tp = inHi; inHi = outHi; outHi = tp;
        tp = inLo; inLo = outLo; outLo = tp;
    }
    // 4 iterations (even) -> final state back in (Ahi, Alo)
}

extern "C" void kernel_launch(void* const* d_in, const int* in_sizes, int n_in,
                              void* d_out, int out_size, void* d_ws, size_t ws_size,
                              hipStream_t stream) {
    const float* x = (const float*)d_in[0];
    const int* ei = (const int*)d_in[1];
    const int* batch = (const int*)d_in[2];
    const float* fc1W = (const float*)d_in[3];
    const float* fc1b = (const float*)d_in[4];
    const float* fc2W = (const float*)d_in[5];
    const float* fc2b = (const float*)d_in[6];
    const float* c1W = (const float*)d_in[7];
    const float* c1wih = (const float*)d_in[8];
    const float* c1whh = (const float*)d_in[9];
    const float* c1bih = (const float*)d_in[10];
    const float* c1bhh = (const float*)d_in[11];
    const float* c2W = (const float*)d_in[12];
    const float* c2wih = (const float*)d_in[13];
    const float* c2whh = (const float*)d_in[14];
    const float* c2bih = (const float*)d_in[15];
    const float* c2bhh = (const float*)d_in[16];
    const float* c3W = (const float*)d_in[17];
    const float* c3wih = (const float*)d_in[18];
    const float* c3whh = (const float*)d_in[19];
    const float* c3bih = (const float*)d_in[20];
    const float* c3bhh = (const float*)d_in[21];
    const float* bn1g = (const float*)d_in[22];
    const float* bn1b = (const float*)d_in[23];
    const float* bn1m = (const float*)d_in[24];
    const float* bn1v = (const float*)d_in[25];
    const float* bn2g = (const float*)d_in[26];
    const float* bn2b = (const float*)d_in[27];
    const float* bn2m = (const float*)d_in[28];
    const float* bn2v = (const float*)d_in[29];

    int N = in_sizes[0] / 32;
    int E = in_sizes[1] / 2;

    const size_t NB = (size_t)N * 128;  // shorts per plane
    unsigned short* PAhi = (unsigned short*)d_ws;  // state pair A
    unsigned short* PAlo = PAhi + NB;
    unsigned short* PBhi = PAlo + NB;              // state pair B (ping-pong)
    unsigned short* PBlo = PBhi + NB;
    unsigned short* Shi = PBlo + NB;               // gathered-S (hi-only)
    unsigned short* Slo = Shi + NB;                // (unused; kept for layout)
    unsigned short* BsHi = Slo + NB;               // 4 layers x 6*C*C <= 393216
    unsigned short* BsLo = BsHi + 393216;
    float* Wc = (float*)(BsLo + 393216);           // 4*C*3C <= 196608 floats
    float* G = Wc + 196608;
    float* G2 = G + 32768;
    int* deg = (int*)(G2 + 65536);
    int* scanout = deg + N;
    int* rowstart = scanout + N;
    int* writeptr = rowstart + N + 1;
    int* blockSums = writeptr + N;
    int* csr_src = blockSums + 64;

    // ---- build CSR by dst (once; reused by all 12 propagation steps) ----
    hipMemsetAsync(deg, 0, (size_t)N * sizeof(int), stream);
    hist_kernel<<<2048, 256, 0, stream>>>(ei, deg, E, N);
    int nscan = (N + 1023) / 1024;
    scan1_kernel<<<nscan, 256, 0, stream>>>(deg, scanout, blockSums, N);
    scan2_kernel<<<1, 64, 0, stream>>>(blockSums, nscan);
    scan3_kernel<<<(N + 255) / 256, 256, 0, stream>>>(scanout, blockSums, rowstart, writeptr, N, E);
    fill_kernel<<<2048, 256, 0, stream>>>(ei, writeptr, csr_src, E, N);

    // x -> pair A hi/lo ([N,32])
    init_x_kernel<<<(N * 32 + 255) / 256, 256, 0, stream>>>(x, PAhi, PAlo, N * 32);

    // conv1 (C=32): state PA, ping-pong with PB
    run_conv<32>(PAhi, PAlo, PBhi, PBlo, Shi, Wc, BsHi, BsLo,
                 c1W, c1wih, c1whh, c1bih, c1bhh, rowstart, csr_src, N, E, stream);
    elu_bn_pad_kernel<32, 64><<<(int)(((long)N * 64 + 255) / 256), 256, 0, stream>>>(
        PAhi, PAlo, PBhi, PBlo, bn1g, bn1b, bn1m, bn1v, N);

    // conv2 (C=64): state PB, ping-pong with PA
    run_conv<64>(PBhi, PBlo, PAhi, PAlo, Shi, Wc, BsHi, BsLo,
                 c2W, c2wih, c2whh, c2bih, c2bhh, rowstart, csr_src, N, E, stream);
    elu_bn_pad_kernel<64, 128><<<(int)(((long)N * 128 + 255) / 256), 256, 0, stream>>>(
        PBhi, PBlo, PAhi, PAlo, bn2g, bn2b, bn2m, bn2v, N);

    // conv3 (C=128): state PA, ping-pong with PB
    run_conv<128>(PAhi, PAlo, PBhi, PBlo, Shi, Wc, BsHi, BsLo,
                  c3W, c3wih, c3whh, c3bih, c3bhh, rowstart, csr_src, N, E, stream);

    // pool (reads pair A, stride 128)
    hipMemsetAsync(G, 0, 256 * 128 * sizeof(float), stream);
    pool_elu_kernel<<<(int)(((long)N * 128 + 255) / 256), 256, 0, stream>>>(
        PAhi, PAlo, batch, G, N);

    fc1_kernel<<<256, 256, 0, stream>>>(G, fc1W, fc1b, G2);
    fc2_logsoftmax_kernel<<<256, 64, 0, stream>>>(G2, fc2W, fc2b, (float*)d_out);
}

// Round 11
// 793.662 us; speedup vs baseline: 3.4020x; 1.0667x over previous
//
#include <hip/hip_runtime.h>
#include <math.h>

// ---------------------------------------------------------------------------
// GNN: 3x GatedGraphConv (C=32,64,128; 4 inner layers each) + BN + pool + MLP
// Round 26: r25 (847 us) + SINGLE-bf16 state (drop the state LO plane).
// Calibration from r23/r24: dropping a 0.009-class term failed (4.75);
// dropping the 0.0023-class B_lo*H term was FREE (absmax 0.5 unchanged).
// State-lo's entire contribution (H_lo*B_hi) is the same 0.0023 class, and
// gather already consumes state hi-only. H-half: A=H_hi x B=hi -> 1 MFMA/acc
// (GRU MFMA 192->144); Hout single plane (WRITE halves); init/bn/pool halve.
// S-half unchanged (A=S_hi, B=hi+lo -- the term that matters).
// ---------------------------------------------------------------------------

#define EPS_BN 1e-5f

typedef short short8 __attribute__((ext_vector_type(8)));
typedef unsigned short u16x8 __attribute__((ext_vector_type(8)));
typedef float f32x4 __attribute__((ext_vector_type(4)));

__device__ __forceinline__ float elu_f(float v) {
    return v > 0.f ? v : expm1f(v);
}
__device__ __forceinline__ float sigmoid_f(float v) {
    return 1.f / (1.f + __expf(-v));
}
__device__ __forceinline__ float tanh_f(float v) {
    float e = __expf(2.f * v);
    return 1.f - 2.f / (e + 1.f);
}
__device__ __forceinline__ unsigned short f2bf(float f) {
    unsigned u = __float_as_uint(f);
    unsigned r = (u + 0x7FFF + ((u >> 16) & 1)) >> 16;
    return (unsigned short)r;
}
__device__ __forceinline__ float bf2f(unsigned short b) {
    return __uint_as_float(((unsigned)b) << 16);
}

// ------------------------- CSR construction -------------------------------
// hist/fill: dst-range partitioned over 8 XCD-heuristic groups (r25).

__global__ __launch_bounds__(256) void hist_kernel(
    const int* __restrict__ ei, int* __restrict__ deg, int E, int N) {
    int part = blockIdx.x & 7;
    int blk = blockIdx.x >> 3;
    int nblk = gridDim.x >> 3;
    int lo = (int)((long)N * part >> 3);
    int hi = (int)((long)N * (part + 1) >> 3);
    for (int e = blk * 256 + threadIdx.x; e < E; e += nblk * 256) {
        int d = ei[E + e];
        if (d >= lo && d < hi) atomicAdd(&deg[d], 1);
    }
}

__global__ __launch_bounds__(256) void scan1_kernel(
    const int* __restrict__ deg, int* __restrict__ out,
    int* __restrict__ blockSums, int N) {
    __shared__ int sdata[256];
    int b = blockIdx.x, t = threadIdx.x;
    int base = b * 1024 + t * 4;
    int v[4], s = 0;
#pragma unroll
    for (int i = 0; i < 4; ++i) {
        v[i] = (base + i < N) ? deg[base + i] : 0;
        s += v[i];
    }
    sdata[t] = s;
    __syncthreads();
    for (int off = 1; off < 256; off <<= 1) {
        int x = (t >= off) ? sdata[t - off] : 0;
        __syncthreads();
        sdata[t] += x;
        __syncthreads();
    }
    int run = sdata[t] - s;
#pragma unroll
    for (int i = 0; i < 4; ++i) {
        if (base + i < N) out[base + i] = run;
        run += v[i];
    }
    if (t == 255) blockSums[b] = sdata[255];
}

__global__ void scan2_kernel(int* blockSums, int nb) {
    if (threadIdx.x == 0 && blockIdx.x == 0) {
        int run = 0;
        for (int i = 0; i < nb; ++i) {
            int v = blockSums[i];
            blockSums[i] = run;
            run += v;
        }
    }
}

__global__ __launch_bounds__(256) void scan3_kernel(
    const int* __restrict__ out, const int* __restrict__ blockSums,
    int* __restrict__ rowstart, int* __restrict__ writeptr, int N, int E) {
    int i = blockIdx.x * 256 + threadIdx.x;
    if (i < N) {
        int v = out[i] + blockSums[i >> 10];
        rowstart[i] = v;
        writeptr[i] = v;
    }
    if (i == 0) rowstart[N] = E;
}

__global__ __launch_bounds__(256) void fill_kernel(
    const int* __restrict__ ei, int* __restrict__ writeptr,
    int* __restrict__ csr_src, int E, int N) {
    int part = blockIdx.x & 7;
    int blk = blockIdx.x >> 3;
    int nblk = gridDim.x >> 3;
    int lo = (int)((long)N * part >> 3);
    int hi = (int)((long)N * (part + 1) >> 3);
    for (int e = blk * 256 + threadIdx.x; e < E; e += nblk * 256) {
        int d = ei[E + e];
        if (d >= lo && d < hi) {
            int p = atomicAdd(&writeptr[d], 1);
            csr_src[p] = ei[e];
        }
    }
}

// ------------------------- Wc = W[l] @ wih^T ------------------------------

template <int C>
__global__ __launch_bounds__(256) void wc_kernel(
    const float* __restrict__ W, const float* __restrict__ wih,
    float* __restrict__ Wc) {
    int idx = blockIdx.x * 256 + threadIdx.x;
    if (idx >= 4 * C * 3 * C) return;
    int l = idx / (C * 3 * C);
    int r = idx % (C * 3 * C);
    int k = r / (3 * C);
    int row = r % (3 * C);
    const float* wrow = W + ((size_t)l * C + k) * C;
    const float* irow = wih + (size_t)row * C;
    float acc = 0.f;
#pragma unroll 4
    for (int t = 0; t < C; ++t) acc += wrow[t] * irow[t];
    Wc[idx] = acc;
}

// ------------------------- B2 swizzle (hi/lo, all 4 layers) ---------------
// mfma_f32_16x16x32_bf16:
//   A[m][k]: m = lane&15, k = (lane>>4)*8 + j
//   B[k][n]: n = lane&15, k = (lane>>4)*8 + j
//   C/D:     col = lane&15, row = (lane>>4)*4 + reg
// GRU concat-B: K = 2C (k<C: Wc_l on S; k>=C: whh on H).
// tslot per ks: [0,CT): r ; [CT,2CT): z ; [2CT,3CT): k<C ? in : hn
// BsLo only consumed for k<C (S-half) since r24.

template <int C>
__global__ __launch_bounds__(256) void swizzle_b2_kernel(
    const float* __restrict__ Wc, const float* __restrict__ whh,
    unsigned short* __restrict__ BsHi, unsigned short* __restrict__ BsLo) {
    constexpr int CT = C / 16;
    int idx = blockIdx.x * 256 + threadIdx.x;
    if (idx >= 4 * 6 * C * C) return;
    int l = idx / (6 * C * C);
    int r0 = idx % (6 * C * C);
    int j = r0 & 7;
    int lane = (r0 >> 3) & 63;
    int rest = r0 >> 9;
    int tslot = rest % (3 * CT);
    int ks = rest / (3 * CT);
    int k = ks * 32 + (lane >> 4) * 8 + j;
    int g = tslot / CT;
    int lt = tslot % CT;
    int c = lt * 16 + (lane & 15);
    int row = g * C + c;
    float v = (k < C) ? Wc[((size_t)l * C + k) * 3 * C + row]
                      : whh[(size_t)row * C + (k - C)];
    unsigned short h = f2bf(v);
    BsHi[idx] = h;
    BsLo[idx] = f2bf(v - bf2f(h));
}

// ------------------------- gather: S[d] = sum X[src] ----------------------
// (identical to r15/r18; state is single-plane now, same read path)

template <int C>
__global__ __launch_bounds__(256) void gather_kernel(
    const unsigned short* __restrict__ Xhi,
    const int* __restrict__ rowstart, const int* __restrict__ csr_src,
    unsigned short* __restrict__ Shi, int N) {
    constexpr int LPG = C / 8;
    constexpr int GPB = 256 / LPG;
    int lane = threadIdx.x % LPG;
    int grp = threadIdx.x / LPG;
    int d = blockIdx.x * GPB + grp;
    if (d >= N) return;
    int p = rowstart[d];
    int p1 = rowstart[d + 1];
    float a[8];
#pragma unroll
    for (int j = 0; j < 8; ++j) a[j] = 0.f;
    int off = lane * 8;
    for (; p + 3 < p1; p += 4) {
        int s0 = csr_src[p];
        int s1 = csr_src[p + 1];
        int s2 = csr_src[p + 2];
        int s3 = csr_src[p + 3];
        u16x8 h0 = *(const u16x8*)(Xhi + (size_t)s0 * C + off);
        u16x8 h1 = *(const u16x8*)(Xhi + (size_t)s1 * C + off);
        u16x8 h2 = *(const u16x8*)(Xhi + (size_t)s2 * C + off);
        u16x8 h3 = *(const u16x8*)(Xhi + (size_t)s3 * C + off);
#pragma unroll
        for (int j = 0; j < 8; ++j) {
            a[j] += (bf2f(h0[j]) + bf2f(h1[j])) + (bf2f(h2[j]) + bf2f(h3[j]));
        }
    }
    for (; p < p1; ++p) {
        int s0 = csr_src[p];
        u16x8 h0 = *(const u16x8*)(Xhi + (size_t)s0 * C + off);
#pragma unroll
        for (int j = 0; j < 8; ++j) a[j] += bf2f(h0[j]);
    }
    size_t base = (size_t)d * C + off;
#pragma unroll
    for (int j = 0; j < 8; ++j) Shi[base + j] = f2bf(a[j]);
}

// ------------------------- GRU cell (C = 64 / 128) ------------------------
// Block = 4 waves = NT nodes (TPW = NT/16 A-tiles per wave). Wave w owns
// column tiles [w*CTW,(w+1)*CTW) of every gate. Out-of-place ping-pong.
// r26 precision config:
//   S-half (k<C):  A = S_hi, B = hi+lo -> 2 MFMA/acc (|S|-scaled term kept)
//   H-half (k>=C): A = H_hi, B = hi    -> 1 MFMA/acc (0.0023-class terms
//                                        dropped; proven free in r24)

template <int C, int NT, int MINW>
__global__ __launch_bounds__(256, MINW) void gru_mfma_kernel(
    const unsigned short* __restrict__ Hin,
    unsigned short* __restrict__ Hout,
    const unsigned short* __restrict__ Shi,
    const unsigned short* __restrict__ BsHi, const unsigned short* __restrict__ BsLo,
    const float* __restrict__ biasI, const float* __restrict__ biasH, int N) {
    constexpr int CT = C / 16;
    constexpr int KS = C / 16;  // 2C/32 k-steps
    constexpr int CTW = CT / 4;
    constexpr int TPW = NT / 16;  // node-tiles per wave
    int wave = threadIdx.x >> 6;
    int lane = threadIdx.x & 63;
    int quad = lane >> 4;
    int l16 = lane & 15;
    int node0 = blockIdx.x * NT;
    int arow[TPW];
#pragma unroll
    for (int t = 0; t < TPW; ++t) {
        int r = node0 + t * 16 + l16;
        arow[t] = r < N ? r : N - 1;
    }
    f32x4 accR[CTW][TPW], accZ[CTW][TPW], accN[CTW][TPW], accH[CTW][TPW];
#pragma unroll
    for (int ct = 0; ct < CTW; ++ct)
#pragma unroll
        for (int t = 0; t < TPW; ++t) {
            accR[ct][t] = (f32x4){0.f, 0.f, 0.f, 0.f};
            accZ[ct][t] = (f32x4){0.f, 0.f, 0.f, 0.f};
            accN[ct][t] = (f32x4){0.f, 0.f, 0.f, 0.f};
            accH[ct][t] = (f32x4){0.f, 0.f, 0.f, 0.f};
        }
    const short8* bhi = (const short8*)BsHi;
    const short8* blo = (const short8*)BsLo;

    // ---- S half (k < C): A = S_hi, B = hi+lo (2 MFMA per acc) ----
    for (int ks = 0; ks < KS / 2; ++ks) {
        int k0 = ks * 32 + quad * 8;
        short8 ahi[TPW];
#pragma unroll
        for (int t = 0; t < TPW; ++t)
            ahi[t] = *(const short8*)(Shi + (size_t)arow[t] * C + k0);
#pragma unroll
        for (int ct = 0; ct < CTW; ++ct) {
            int ts = ks * 3 * CT + wave * CTW + ct;
            short8 bhf = bhi[(size_t)ts * 64 + lane];
            short8 blf = blo[(size_t)ts * 64 + lane];
#pragma unroll
            for (int t = 0; t < TPW; ++t) {
                accR[ct][t] = __builtin_amdgcn_mfma_f32_16x16x32_bf16(ahi[t], bhf, accR[ct][t], 0, 0, 0);
                accR[ct][t] = __builtin_amdgcn_mfma_f32_16x16x32_bf16(ahi[t], blf, accR[ct][t], 0, 0, 0);
            }
            bhf = bhi[(size_t)(ts + CT) * 64 + lane];
            blf = blo[(size_t)(ts + CT) * 64 + lane];
#pragma unroll
            for (int t = 0; t < TPW; ++t) {
                accZ[ct][t] = __builtin_amdgcn_mfma_f32_16x16x32_bf16(ahi[t], bhf, accZ[ct][t], 0, 0, 0);
                accZ[ct][t] = __builtin_amdgcn_mfma_f32_16x16x32_bf16(ahi[t], blf, accZ[ct][t], 0, 0, 0);
            }
            bhf = bhi[(size_t)(ts + 2 * CT) * 64 + lane];
            blf = blo[(size_t)(ts + 2 * CT) * 64 + lane];
#pragma unroll
            for (int t = 0; t < TPW; ++t) {
                accN[ct][t] = __builtin_amdgcn_mfma_f32_16x16x32_bf16(ahi[t], bhf, accN[ct][t], 0, 0, 0);
                accN[ct][t] = __builtin_amdgcn_mfma_f32_16x16x32_bf16(ahi[t], blf, accN[ct][t], 0, 0, 0);
            }
        }
    }
    // ---- H half (k >= C): A = H_hi, B = hi only (1 MFMA per acc) ----
    for (int ks = KS / 2; ks < KS; ++ks) {
        int k0 = ks * 32 + quad * 8 - C;
        short8 ahi[TPW];
#pragma unroll
        for (int t = 0; t < TPW; ++t)
            ahi[t] = *(const short8*)(Hin + (size_t)arow[t] * C + k0);
#pragma unroll
        for (int ct = 0; ct < CTW; ++ct) {
            int ts = ks * 3 * CT + wave * CTW + ct;
            short8 bhf = bhi[(size_t)ts * 64 + lane];
#pragma unroll
            for (int t = 0; t < TPW; ++t)
                accR[ct][t] = __builtin_amdgcn_mfma_f32_16x16x32_bf16(ahi[t], bhf, accR[ct][t], 0, 0, 0);
            bhf = bhi[(size_t)(ts + CT) * 64 + lane];
#pragma unroll
            for (int t = 0; t < TPW; ++t)
                accZ[ct][t] = __builtin_amdgcn_mfma_f32_16x16x32_bf16(ahi[t], bhf, accZ[ct][t], 0, 0, 0);
            bhf = bhi[(size_t)(ts + 2 * CT) * 64 + lane];
#pragma unroll
            for (int t = 0; t < TPW; ++t)
                accH[ct][t] = __builtin_amdgcn_mfma_f32_16x16x32_bf16(ahi[t], bhf, accH[ct][t], 0, 0, 0);
        }
    }

#pragma unroll
    for (int ct = 0; ct < CTW; ++ct) {
        int c = (wave * CTW + ct) * 16 + l16;
        float bir = biasI[c], biz = biasI[C + c], bin = biasI[2 * C + c];
        float bhr = biasH[c], bhz = biasH[C + c], bhn = biasH[2 * C + c];
#pragma unroll
        for (int t = 0; t < TPW; ++t) {
#pragma unroll
            for (int r = 0; r < 4; ++r) {
                int node = node0 + t * 16 + quad * 4 + r;
                if (node < N) {
                    size_t gi = (size_t)node * C + c;
                    float xo = bf2f(Hin[gi]);
                    float rv = sigmoid_f(accR[ct][t][r] + bir + bhr);
                    float zv = sigmoid_f(accZ[ct][t][r] + biz + bhz);
                    float nv = tanh_f(accN[ct][t][r] + bin + rv * (accH[ct][t][r] + bhn));
                    Hout[gi] = f2bf((1.f - zv) * nv + zv * xo);
                }
            }
        }
    }
}

// C=32 GRU: 1 A-tile per wave, out-of-place; r26 precision config
__global__ __launch_bounds__(256, 4) void gru32_kernel(
    const unsigned short* __restrict__ Hin,
    unsigned short* __restrict__ Hout,
    const unsigned short* __restrict__ Shi,
    const unsigned short* __restrict__ BsHi, const unsigned short* __restrict__ BsLo,
    const float* __restrict__ biasI, const float* __restrict__ biasH, int N) {
    constexpr int C = 32;
    constexpr int CT = 2;
    int wave = threadIdx.x >> 6;
    int lane = threadIdx.x & 63;
    int quad = lane >> 4;
    int l16 = lane & 15;
    int node0 = blockIdx.x * 64 + wave * 16;
    int ar = node0 + l16;
    if (ar >= N) ar = N - 1;
    f32x4 accR[CT], accZ[CT], accN[CT], accH[CT];
#pragma unroll
    for (int t = 0; t < CT; ++t) {
        accR[t] = (f32x4){0.f, 0.f, 0.f, 0.f};
        accZ[t] = (f32x4){0.f, 0.f, 0.f, 0.f};
        accN[t] = (f32x4){0.f, 0.f, 0.f, 0.f};
        accH[t] = (f32x4){0.f, 0.f, 0.f, 0.f};
    }
    const short8* bhi = (const short8*)BsHi;
    const short8* blo = (const short8*)BsLo;
    int k0 = quad * 8;
    {  // ks = 0: S half (A=S_hi, B hi+lo: 2 ops)
        short8 ahi = *(const short8*)(Shi + (size_t)ar * C + k0);
#pragma unroll
        for (int g = 0; g < 3; ++g) {
            f32x4* acc = g == 0 ? accR : (g == 1 ? accZ : accN);
#pragma unroll
            for (int t = 0; t < CT; ++t) {
                int ts = g * CT + t;
                short8 bhf = bhi[(size_t)ts * 64 + lane];
                short8 blf = blo[(size_t)ts * 64 + lane];
                acc[t] = __builtin_amdgcn_mfma_f32_16x16x32_bf16(ahi, bhf, acc[t], 0, 0, 0);
                acc[t] = __builtin_amdgcn_mfma_f32_16x16x32_bf16(ahi, blf, acc[t], 0, 0, 0);
            }
        }
    }
    {  // ks = 1: H half (A=H_hi, B hi only: 1 op)
        short8 ahi = *(const short8*)(Hin + (size_t)ar * C + k0);
#pragma unroll
        for (int g = 0; g < 3; ++g) {
            f32x4* acc = g == 0 ? accR : (g == 1 ? accZ : accH);
#pragma unroll
            for (int t = 0; t < CT; ++t) {
                int ts = 3 * CT + g * CT + t;
                short8 bhf = bhi[(size_t)ts * 64 + lane];
                acc[t] = __builtin_amdgcn_mfma_f32_16x16x32_bf16(ahi, bhf, acc[t], 0, 0, 0);
            }
        }
    }
#pragma unroll
    for (int t = 0; t < CT; ++t) {
        int c = t * 16 + l16;
        float bir = biasI[c], biz = biasI[C + c], bin = biasI[2 * C + c];
        float bhr = biasH[c], bhz = biasH[C + c], bhn = biasH[2 * C + c];
#pragma unroll
        for (int r = 0; r < 4; ++r) {
            int node = node0 + quad * 4 + r;
            if (node < N) {
                size_t gi = (size_t)node * C + c;
                float xo = bf2f(Hin[gi]);
                float rv = sigmoid_f(accR[t][r] + bir + bhr);
                float zv = sigmoid_f(accZ[t][r] + biz + bhz);
                float nv = tanh_f(accN[t][r] + bin + rv * (accH[t][r] + bhn));
                Hout[gi] = f2bf((1.f - zv) * nv + zv * xo);
            }
        }
    }
}

// ------------------------- epilogues --------------------------------------

__global__ __launch_bounds__(256) void init_x_kernel(
    const float* __restrict__ x, unsigned short* __restrict__ H, int total) {
    int t = blockIdx.x * 256 + threadIdx.x;
    if (t < total) H[t] = f2bf(x[t]);
}

template <int Cin, int Cout>
__global__ __launch_bounds__(256) void elu_bn_pad_kernel(
    const unsigned short* __restrict__ S, unsigned short* __restrict__ D,
    const float* __restrict__ gamma, const float* __restrict__ beta,
    const float* __restrict__ mean, const float* __restrict__ var, int N) {
    long t = (long)blockIdx.x * 256 + threadIdx.x;
    long total = (long)N * Cout;
    if (t >= total) return;
    int n = (int)(t / Cout);
    int c = (int)(t & (Cout - 1));
    float v = 0.f;
    if (c < Cin) {
        size_t si = (size_t)n * Cin + c;
        float x = bf2f(S[si]);
        x = elu_f(x);
        v = (x - mean[c]) * rsqrtf(var[c] + EPS_BN) * gamma[c] + beta[c];
    }
    D[t] = f2bf(v);
}

__global__ __launch_bounds__(256) void pool_elu_kernel(
    const unsigned short* __restrict__ H,
    const int* __restrict__ batch, float* __restrict__ G, int N) {
    long t = (long)blockIdx.x * 256 + threadIdx.x;
    if (t >= (long)N * 128) return;
    int n = (int)(t >> 7);
    int c = (int)(t & 127);
    float v = elu_f(bf2f(H[t]));
    atomicAdd(&G[batch[n] * 128 + c], v);
}

__global__ __launch_bounds__(256) void fc1_kernel(
    const float* __restrict__ G, const float* __restrict__ W,
    const float* __restrict__ b, float* __restrict__ G2) {
    __shared__ float row[128];
    int g = blockIdx.x;
    int j = threadIdx.x;
    if (j < 128) row[j] = G[g * 128 + j];
    __syncthreads();
    float acc = b[j];
    for (int k = 0; k < 128; ++k) acc += row[k] * W[j * 128 + k];
    G2[g * 256 + j] = elu_f(acc);
}

__global__ __launch_bounds__(64) void fc2_logsoftmax_kernel(
    const float* __restrict__ G2, const float* __restrict__ W,
    const float* __restrict__ b, float* __restrict__ out) {
    __shared__ float row[256];
    __shared__ float logits[10];
    __shared__ float red[2];
    int g = blockIdx.x;
    int tid = threadIdx.x;
    for (int i = tid; i < 256; i += 64) row[i] = G2[g * 256 + i];
    __syncthreads();
    if (tid < 10) {
        float acc = b[tid];
        for (int k = 0; k < 256; ++k) acc += row[k] * W[tid * 256 + k];
        logits[tid] = acc;
    }
    __syncthreads();
    if (tid == 0) {
        float m = -1e30f;
        for (int a = 0; a < 10; ++a) m = fmaxf(m, logits[a]);
        float s = 0.f;
        for (int a = 0; a < 10; ++a) s += expf(logits[a] - m);
        red[0] = m;
        red[1] = logf(s);
    }
    __syncthreads();
    if (tid < 10) out[g * 10 + tid] = logits[tid] - red[0] - red[1];
}

// ---------------------------------------------------------------------------

template <int C>
static void run_conv(unsigned short* A, unsigned short* B,
                     unsigned short* Shi,
                     float* Wc, unsigned short* BsHi, unsigned short* BsLo,
                     const float* W, const float* wih, const float* whh,
                     const float* bih, const float* bhh,
                     const int* rowstart, const int* csr_src,
                     int N, int E, hipStream_t stream) {
    wc_kernel<C><<<(4 * C * 3 * C + 255) / 256, 256, 0, stream>>>(W, wih, Wc);
    swizzle_b2_kernel<C><<<(4 * 6 * C * C + 255) / 256, 256, 0, stream>>>(Wc, whh, BsHi, BsLo);
    constexpr int NT = (C == 128) ? 32 : 64;  // nodes per GRU block
    int nb = (N + NT - 1) / NT;
    constexpr int GPB = 2048 / C;  // gather dst-groups per block (C/8 lanes)
    int gblocks = (N + GPB - 1) / GPB;
    unsigned short *in = A, *out = B;
    for (int it = 0; it < 4; ++it) {
        gather_kernel<C><<<gblocks, 256, 0, stream>>>(
            in, rowstart, csr_src, Shi, N);
        const unsigned short* bs_h = BsHi + (size_t)it * 6 * C * C;
        const unsigned short* bs_l = BsLo + (size_t)it * 6 * C * C;
        if constexpr (C == 32)
            gru32_kernel<<<nb, 256, 0, stream>>>(
                in, out, Shi, bs_h, bs_l, bih, bhh, N);
        else
            gru_mfma_kernel<C, NT, 3><<<nb, 256, 0, stream>>>(
                in, out, Shi, bs_h, bs_l, bih, bhh, N);
        unsigned short* tp = in; in = out; out = tp;
    }
    // 4 iterations (even) -> final state back in A
}

extern "C" void kernel_launch(void* const* d_in, const int* in_sizes, int n_in,
                              void* d_out, int out_size, void* d_ws, size_t ws_size,
                              hipStream_t stream) {
    const float* x = (const float*)d_in[0];
    const int* ei = (const int*)d_in[1];
    const int* batch = (const int*)d_in[2];
    const float* fc1W = (const float*)d_in[3];
    const float* fc1b = (const float*)d_in[4];
    const float* fc2W = (const float*)d_in[5];
    const float* fc2b = (const float*)d_in[6];
    const float* c1W = (const float*)d_in[7];
    const float* c1wih = (const float*)d_in[8];
    const float* c1whh = (const float*)d_in[9];
    const float* c1bih = (const float*)d_in[10];
    const float* c1bhh = (const float*)d_in[11];
    const float* c2W = (const float*)d_in[12];
    const float* c2wih = (const float*)d_in[13];
    const float* c2whh = (const float*)d_in[14];
    const float* c2bih = (const float*)d_in[15];
    const float* c2bhh = (const float*)d_in[16];
    const float* c3W = (const float*)d_in[17];
    const float* c3wih = (const float*)d_in[18];
    const float* c3whh = (const float*)d_in[19];
    const float* c3bih = (const float*)d_in[20];
    const float* c3bhh = (const float*)d_in[21];
    const float* bn1g = (const float*)d_in[22];
    const float* bn1b = (const float*)d_in[23];
    const float* bn1m = (const float*)d_in[24];
    const float* bn1v = (const float*)d_in[25];
    const float* bn2g = (const float*)d_in[26];
    const float* bn2b = (const float*)d_in[27];
    const float* bn2m = (const float*)d_in[28];
    const float* bn2v = (const float*)d_in[29];

    int N = in_sizes[0] / 32;
    int E = in_sizes[1] / 2;

    const size_t NB = (size_t)N * 128;  // shorts per plane
    unsigned short* PA = (unsigned short*)d_ws;    // state A (single plane)
    unsigned short* PB = PA + NB;                  // state B (ping-pong)
    unsigned short* Shi = PB + NB;                 // gathered-S (hi-only)
    unsigned short* BsHi = Shi + NB;               // 4 layers x 6*C*C <= 393216
    unsigned short* BsLo = BsHi + 393216;
    float* Wc = (float*)(BsLo + 393216);           // 4*C*3C <= 196608 floats
    float* G = Wc + 196608;
    float* G2 = G + 32768;
    int* deg = (int*)(G2 + 65536);
    int* scanout = deg + N;
    int* rowstart = scanout + N;
    int* writeptr = rowstart + N + 1;
    int* blockSums = writeptr + N;
    int* csr_src = blockSums + 64;

    // ---- build CSR by dst (once; reused by all 12 propagation steps) ----
    hipMemsetAsync(deg, 0, (size_t)N * sizeof(int), stream);
    hist_kernel<<<2048, 256, 0, stream>>>(ei, deg, E, N);
    int nscan = (N + 1023) / 1024;
    scan1_kernel<<<nscan, 256, 0, stream>>>(deg, scanout, blockSums, N);
    scan2_kernel<<<1, 64, 0, stream>>>(blockSums, nscan);
    scan3_kernel<<<(N + 255) / 256, 256, 0, stream>>>(scanout, blockSums, rowstart, writeptr, N, E);
    fill_kernel<<<2048, 256, 0, stream>>>(ei, writeptr, csr_src, E, N);

    // x -> state A ([N,32] bf16)
    init_x_kernel<<<(N * 32 + 255) / 256, 256, 0, stream>>>(x, PA, N * 32);

    // conv1 (C=32): state PA, ping-pong with PB
    run_conv<32>(PA, PB, Shi, Wc, BsHi, BsLo,
                 c1W, c1wih, c1whh, c1bih, c1bhh, rowstart, csr_src, N, E, stream);
    elu_bn_pad_kernel<32, 64><<<(int)(((long)N * 64 + 255) / 256), 256, 0, stream>>>(
        PA, PB, bn1g, bn1b, bn1m, bn1v, N);

    // conv2 (C=64): state PB, ping-pong with PA
    run_conv<64>(PB, PA, Shi, Wc, BsHi, BsLo,
                 c2W, c2wih, c2whh, c2bih, c2bhh, rowstart, csr_src, N, E, stream);
    elu_bn_pad_kernel<64, 128><<<(int)(((long)N * 128 + 255) / 256), 256, 0, stream>>>(
        PB, PA, bn2g, bn2b, bn2m, bn2v, N);

    // conv3 (C=128): state PA, ping-pong with PB
    run_conv<128>(PA, PB, Shi, Wc, BsHi, BsLo,
                  c3W, c3wih, c3whh, c3bih, c3bhh, rowstart, csr_src, N, E, stream);

    // pool (reads state PA, stride 128)
    hipMemsetAsync(G, 0, 256 * 128 * sizeof(float), stream);
    pool_elu_kernel<<<(int)(((long)N * 128 + 255) / 256), 256, 0, stream>>>(
        PA, batch, G, N);

    fc1_kernel<<<256, 256, 0, stream>>>(G, fc1W, fc1b, G2);
    fc2_logsoftmax_kernel<<<256, 64, 0, stream>>>(G2, fc2W, fc2b, (float*)d_out);
}

// Round 12
// 783.207 us; speedup vs baseline: 3.4474x; 1.0133x over previous
//
#include <hip/hip_runtime.h>
#include <math.h>

// ---------------------------------------------------------------------------
// GNN: 3x GatedGraphConv (C=32,64,128; 4 inner layers each) + BN + pool + MLP
// Round 27: r26 (794 us) + three independent trims:
//  1) gather: 8-deep edge pipeline (was 4) -- standalone gather runs at high
//     occupancy, so deeper per-thread MLP is additive (unlike fused r17).
//  2) wc+swizzle for all 3 convs merged into 2 up-front dispatches (was 6
//     interleaved in the critical path).
//  3) pool: batch-sorted pair reduction halves atomics.
// Precision config unchanged from r26 (S-half B hi+lo; H-half A/B hi-only;
// single-bf16 state). CSR build unchanged from r25.
// ---------------------------------------------------------------------------

#define EPS_BN 1e-5f

typedef short short8 __attribute__((ext_vector_type(8)));
typedef unsigned short u16x8 __attribute__((ext_vector_type(8)));
typedef float f32x4 __attribute__((ext_vector_type(4)));

__device__ __forceinline__ float elu_f(float v) {
    return v > 0.f ? v : expm1f(v);
}
__device__ __forceinline__ float sigmoid_f(float v) {
    return 1.f / (1.f + __expf(-v));
}
__device__ __forceinline__ float tanh_f(float v) {
    float e = __expf(2.f * v);
    return 1.f - 2.f / (e + 1.f);
}
__device__ __forceinline__ unsigned short f2bf(float f) {
    unsigned u = __float_as_uint(f);
    unsigned r = (u + 0x7FFF + ((u >> 16) & 1)) >> 16;
    return (unsigned short)r;
}
__device__ __forceinline__ float bf2f(unsigned short b) {
    return __uint_as_float(((unsigned)b) << 16);
}

// ------------------------- CSR construction -------------------------------
// hist/fill: dst-range partitioned over 8 XCD-heuristic groups (r25).

__global__ __launch_bounds__(256) void hist_kernel(
    const int* __restrict__ ei, int* __restrict__ deg, int E, int N) {
    int part = blockIdx.x & 7;
    int blk = blockIdx.x >> 3;
    int nblk = gridDim.x >> 3;
    int lo = (int)((long)N * part >> 3);
    int hi = (int)((long)N * (part + 1) >> 3);
    for (int e = blk * 256 + threadIdx.x; e < E; e += nblk * 256) {
        int d = ei[E + e];
        if (d >= lo && d < hi) atomicAdd(&deg[d], 1);
    }
}

__global__ __launch_bounds__(256) void scan1_kernel(
    const int* __restrict__ deg, int* __restrict__ out,
    int* __restrict__ blockSums, int N) {
    __shared__ int sdata[256];
    int b = blockIdx.x, t = threadIdx.x;
    int base = b * 1024 + t * 4;
    int v[4], s = 0;
#pragma unroll
    for (int i = 0; i < 4; ++i) {
        v[i] = (base + i < N) ? deg[base + i] : 0;
        s += v[i];
    }
    sdata[t] = s;
    __syncthreads();
    for (int off = 1; off < 256; off <<= 1) {
        int x = (t >= off) ? sdata[t - off] : 0;
        __syncthreads();
        sdata[t] += x;
        __syncthreads();
    }
    int run = sdata[t] - s;
#pragma unroll
    for (int i = 0; i < 4; ++i) {
        if (base + i < N) out[base + i] = run;
        run += v[i];
    }
    if (t == 255) blockSums[b] = sdata[255];
}

__global__ void scan2_kernel(int* blockSums, int nb) {
    if (threadIdx.x == 0 && blockIdx.x == 0) {
        int run = 0;
        for (int i = 0; i < nb; ++i) {
            int v = blockSums[i];
            blockSums[i] = run;
            run += v;
        }
    }
}

__global__ __launch_bounds__(256) void scan3_kernel(
    const int* __restrict__ out, const int* __restrict__ blockSums,
    int* __restrict__ rowstart, int* __restrict__ writeptr, int N, int E) {
    int i = blockIdx.x * 256 + threadIdx.x;
    if (i < N) {
        int v = out[i] + blockSums[i >> 10];
        rowstart[i] = v;
        writeptr[i] = v;
    }
    if (i == 0) rowstart[N] = E;
}

__global__ __launch_bounds__(256) void fill_kernel(
    const int* __restrict__ ei, int* __restrict__ writeptr,
    int* __restrict__ csr_src, int E, int N) {
    int part = blockIdx.x & 7;
    int blk = blockIdx.x >> 3;
    int nblk = gridDim.x >> 3;
    int lo = (int)((long)N * part >> 3);
    int hi = (int)((long)N * (part + 1) >> 3);
    for (int e = blk * 256 + threadIdx.x; e < E; e += nblk * 256) {
        int d = ei[E + e];
        if (d >= lo && d < hi) {
            int p = atomicAdd(&writeptr[d], 1);
            csr_src[p] = ei[e];
        }
    }
}

// ---------------- merged Wc + B-swizzle (all 3 convs, 2 dispatches) -------
// Wc[l] = W[l] @ wih^T per conv; element counts: conv1 12288, conv2 49152,
// conv3 196608 (total 258048). Bs: conv1 24576, conv2 98304, conv3 393216
// (total 516096 shorts per plane). Offsets hardcoded below.

__device__ __forceinline__ void wc_one(
    const float* __restrict__ W, const float* __restrict__ wih,
    float* __restrict__ Wc, int idx, int C) {
    int l = idx / (C * 3 * C);
    int r = idx % (C * 3 * C);
    int k = r / (3 * C);
    int row = r % (3 * C);
    const float* wrow = W + ((size_t)l * C + k) * C;
    const float* irow = wih + (size_t)row * C;
    float acc = 0.f;
#pragma unroll 4
    for (int t = 0; t < C; ++t) acc += wrow[t] * irow[t];
    Wc[idx] = acc;
}

__global__ __launch_bounds__(256) void wc_all_kernel(
    const float* __restrict__ W1, const float* __restrict__ wih1,
    const float* __restrict__ W2, const float* __restrict__ wih2,
    const float* __restrict__ W3, const float* __restrict__ wih3,
    float* __restrict__ Wc) {
    int idx = blockIdx.x * 256 + threadIdx.x;
    if (idx < 12288) wc_one(W1, wih1, Wc, idx, 32);
    else if (idx < 61440) wc_one(W2, wih2, Wc + 12288, idx - 12288, 64);
    else if (idx < 258048) wc_one(W3, wih3, Wc + 61440, idx - 61440, 128);
}

// B-fragment swizzle (layout comment in r13/r24): concat-B K=2C, tslot per
// ks: [0,CT): r ; [CT,2CT): z ; [2CT,3CT): k<C ? in : hn. BsLo used only
// for k<C (S-half) since r24.
__device__ __forceinline__ void swz_one(
    const float* __restrict__ Wc, const float* __restrict__ whh,
    unsigned short* __restrict__ BsHi, unsigned short* __restrict__ BsLo,
    int idx, int C) {
    int CT = C / 16;
    int l = idx / (6 * C * C);
    int r0 = idx % (6 * C * C);
    int j = r0 & 7;
    int lane = (r0 >> 3) & 63;
    int rest = r0 >> 9;
    int tslot = rest % (3 * CT);
    int ks = rest / (3 * CT);
    int k = ks * 32 + (lane >> 4) * 8 + j;
    int g = tslot / CT;
    int lt = tslot % CT;
    int c = lt * 16 + (lane & 15);
    int row = g * C + c;
    float v = (k < C) ? Wc[((size_t)l * C + k) * 3 * C + row]
                      : whh[(size_t)row * C + (k - C)];
    unsigned short h = f2bf(v);
    BsHi[idx] = h;
    BsLo[idx] = f2bf(v - bf2f(h));
}

__global__ __launch_bounds__(256) void swizzle_all_kernel(
    const float* __restrict__ Wc,
    const float* __restrict__ whh1, const float* __restrict__ whh2,
    const float* __restrict__ whh3,
    unsigned short* __restrict__ BsHi, unsigned short* __restrict__ BsLo) {
    int idx = blockIdx.x * 256 + threadIdx.x;
    if (idx < 24576)
        swz_one(Wc, whh1, BsHi, BsLo, idx, 32);
    else if (idx < 122880)
        swz_one(Wc + 12288, whh2, BsHi + 24576, BsLo + 24576, idx - 24576, 64);
    else if (idx < 516096)
        swz_one(Wc + 61440, whh3, BsHi + 122880, BsLo + 122880, idx - 122880, 128);
}

// ------------------------- gather: S[d] = sum X[src] ----------------------
// LPG = C/8 lanes per dst, 16B loads, 8-deep edge pipeline (r27).

template <int C>
__global__ __launch_bounds__(256) void gather_kernel(
    const unsigned short* __restrict__ Xhi,
    const int* __restrict__ rowstart, const int* __restrict__ csr_src,
    unsigned short* __restrict__ Shi, int N) {
    constexpr int LPG = C / 8;
    constexpr int GPB = 256 / LPG;
    int lane = threadIdx.x % LPG;
    int grp = threadIdx.x / LPG;
    int d = blockIdx.x * GPB + grp;
    if (d >= N) return;
    int p = rowstart[d];
    int p1 = rowstart[d + 1];
    float a[8];
#pragma unroll
    for (int j = 0; j < 8; ++j) a[j] = 0.f;
    int off = lane * 8;
    for (; p + 7 < p1; p += 8) {
        int s[8];
#pragma unroll
        for (int u = 0; u < 8; ++u) s[u] = csr_src[p + u];
        u16x8 h[8];
#pragma unroll
        for (int u = 0; u < 8; ++u)
            h[u] = *(const u16x8*)(Xhi + (size_t)s[u] * C + off);
#pragma unroll
        for (int u = 0; u < 8; ++u) {
#pragma unroll
            for (int j = 0; j < 8; ++j) a[j] += bf2f(h[u][j]);
        }
    }
    for (; p + 3 < p1; p += 4) {
        int s0 = csr_src[p];
        int s1 = csr_src[p + 1];
        int s2 = csr_src[p + 2];
        int s3 = csr_src[p + 3];
        u16x8 h0 = *(const u16x8*)(Xhi + (size_t)s0 * C + off);
        u16x8 h1 = *(const u16x8*)(Xhi + (size_t)s1 * C + off);
        u16x8 h2 = *(const u16x8*)(Xhi + (size_t)s2 * C + off);
        u16x8 h3 = *(const u16x8*)(Xhi + (size_t)s3 * C + off);
#pragma unroll
        for (int j = 0; j < 8; ++j) {
            a[j] += (bf2f(h0[j]) + bf2f(h1[j])) + (bf2f(h2[j]) + bf2f(h3[j]));
        }
    }
    for (; p < p1; ++p) {
        int s0 = csr_src[p];
        u16x8 h0 = *(const u16x8*)(Xhi + (size_t)s0 * C + off);
#pragma unroll
        for (int j = 0; j < 8; ++j) a[j] += bf2f(h0[j]);
    }
    size_t base = (size_t)d * C + off;
#pragma unroll
    for (int j = 0; j < 8; ++j) Shi[base + j] = f2bf(a[j]);
}

// ------------------------- GRU cell (C = 64 / 128) ------------------------
// r26 precision config:
//   S-half (k<C):  A = S_hi, B = hi+lo -> 2 MFMA/acc
//   H-half (k>=C): A = H_hi, B = hi    -> 1 MFMA/acc

template <int C, int NT, int MINW>
__global__ __launch_bounds__(256, MINW) void gru_mfma_kernel(
    const unsigned short* __restrict__ Hin,
    unsigned short* __restrict__ Hout,
    const unsigned short* __restrict__ Shi,
    const unsigned short* __restrict__ BsHi, const unsigned short* __restrict__ BsLo,
    const float* __restrict__ biasI, const float* __restrict__ biasH, int N) {
    constexpr int CT = C / 16;
    constexpr int KS = C / 16;  // 2C/32 k-steps
    constexpr int CTW = CT / 4;
    constexpr int TPW = NT / 16;  // node-tiles per wave
    int wave = threadIdx.x >> 6;
    int lane = threadIdx.x & 63;
    int quad = lane >> 4;
    int l16 = lane & 15;
    int node0 = blockIdx.x * NT;
    int arow[TPW];
#pragma unroll
    for (int t = 0; t < TPW; ++t) {
        int r = node0 + t * 16 + l16;
        arow[t] = r < N ? r : N - 1;
    }
    f32x4 accR[CTW][TPW], accZ[CTW][TPW], accN[CTW][TPW], accH[CTW][TPW];
#pragma unroll
    for (int ct = 0; ct < CTW; ++ct)
#pragma unroll
        for (int t = 0; t < TPW; ++t) {
            accR[ct][t] = (f32x4){0.f, 0.f, 0.f, 0.f};
            accZ[ct][t] = (f32x4){0.f, 0.f, 0.f, 0.f};
            accN[ct][t] = (f32x4){0.f, 0.f, 0.f, 0.f};
            accH[ct][t] = (f32x4){0.f, 0.f, 0.f, 0.f};
        }
    const short8* bhi = (const short8*)BsHi;
    const short8* blo = (const short8*)BsLo;

    // ---- S half (k < C): A = S_hi, B = hi+lo (2 MFMA per acc) ----
    for (int ks = 0; ks < KS / 2; ++ks) {
        int k0 = ks * 32 + quad * 8;
        short8 ahi[TPW];
#pragma unroll
        for (int t = 0; t < TPW; ++t)
            ahi[t] = *(const short8*)(Shi + (size_t)arow[t] * C + k0);
#pragma unroll
        for (int ct = 0; ct < CTW; ++ct) {
            int ts = ks * 3 * CT + wave * CTW + ct;
            short8 bhf = bhi[(size_t)ts * 64 + lane];
            short8 blf = blo[(size_t)ts * 64 + lane];
#pragma unroll
            for (int t = 0; t < TPW; ++t) {
                accR[ct][t] = __builtin_amdgcn_mfma_f32_16x16x32_bf16(ahi[t], bhf, accR[ct][t], 0, 0, 0);
                accR[ct][t] = __builtin_amdgcn_mfma_f32_16x16x32_bf16(ahi[t], blf, accR[ct][t], 0, 0, 0);
            }
            bhf = bhi[(size_t)(ts + CT) * 64 + lane];
            blf = blo[(size_t)(ts + CT) * 64 + lane];
#pragma unroll
            for (int t = 0; t < TPW; ++t) {
                accZ[ct][t] = __builtin_amdgcn_mfma_f32_16x16x32_bf16(ahi[t], bhf, accZ[ct][t], 0, 0, 0);
                accZ[ct][t] = __builtin_amdgcn_mfma_f32_16x16x32_bf16(ahi[t], blf, accZ[ct][t], 0, 0, 0);
            }
            bhf = bhi[(size_t)(ts + 2 * CT) * 64 + lane];
            blf = blo[(size_t)(ts + 2 * CT) * 64 + lane];
#pragma unroll
            for (int t = 0; t < TPW; ++t) {
                accN[ct][t] = __builtin_amdgcn_mfma_f32_16x16x32_bf16(ahi[t], bhf, accN[ct][t], 0, 0, 0);
                accN[ct][t] = __builtin_amdgcn_mfma_f32_16x16x32_bf16(ahi[t], blf, accN[ct][t], 0, 0, 0);
            }
        }
    }
    // ---- H half (k >= C): A = H_hi, B = hi only (1 MFMA per acc) ----
    for (int ks = KS / 2; ks < KS; ++ks) {
        int k0 = ks * 32 + quad * 8 - C;
        short8 ahi[TPW];
#pragma unroll
        for (int t = 0; t < TPW; ++t)
            ahi[t] = *(const short8*)(Hin + (size_t)arow[t] * C + k0);
#pragma unroll
        for (int ct = 0; ct < CTW; ++ct) {
            int ts = ks * 3 * CT + wave * CTW + ct;
            short8 bhf = bhi[(size_t)ts * 64 + lane];
#pragma unroll
            for (int t = 0; t < TPW; ++t)
                accR[ct][t] = __builtin_amdgcn_mfma_f32_16x16x32_bf16(ahi[t], bhf, accR[ct][t], 0, 0, 0);
            bhf = bhi[(size_t)(ts + CT) * 64 + lane];
#pragma unroll
            for (int t = 0; t < TPW; ++t)
                accZ[ct][t] = __builtin_amdgcn_mfma_f32_16x16x32_bf16(ahi[t], bhf, accZ[ct][t], 0, 0, 0);
            bhf = bhi[(size_t)(ts + 2 * CT) * 64 + lane];
#pragma unroll
            for (int t = 0; t < TPW; ++t)
                accH[ct][t] = __builtin_amdgcn_mfma_f32_16x16x32_bf16(ahi[t], bhf, accH[ct][t], 0, 0, 0);
        }
    }

#pragma unroll
    for (int ct = 0; ct < CTW; ++ct) {
        int c = (wave * CTW + ct) * 16 + l16;
        float bir = biasI[c], biz = biasI[C + c], bin = biasI[2 * C + c];
        float bhr = biasH[c], bhz = biasH[C + c], bhn = biasH[2 * C + c];
#pragma unroll
        for (int t = 0; t < TPW; ++t) {
#pragma unroll
            for (int r = 0; r < 4; ++r) {
                int node = node0 + t * 16 + quad * 4 + r;
                if (node < N) {
                    size_t gi = (size_t)node * C + c;
                    float xo = bf2f(Hin[gi]);
                    float rv = sigmoid_f(accR[ct][t][r] + bir + bhr);
                    float zv = sigmoid_f(accZ[ct][t][r] + biz + bhz);
                    float nv = tanh_f(accN[ct][t][r] + bin + rv * (accH[ct][t][r] + bhn));
                    Hout[gi] = f2bf((1.f - zv) * nv + zv * xo);
                }
            }
        }
    }
}

// C=32 GRU: 1 A-tile per wave, out-of-place; r26 precision config
__global__ __launch_bounds__(256, 4) void gru32_kernel(
    const unsigned short* __restrict__ Hin,
    unsigned short* __restrict__ Hout,
    const unsigned short* __restrict__ Shi,
    const unsigned short* __restrict__ BsHi, const unsigned short* __restrict__ BsLo,
    const float* __restrict__ biasI, const float* __restrict__ biasH, int N) {
    constexpr int C = 32;
    constexpr int CT = 2;
    int wave = threadIdx.x >> 6;
    int lane = threadIdx.x & 63;
    int quad = lane >> 4;
    int l16 = lane & 15;
    int node0 = blockIdx.x * 64 + wave * 16;
    int ar = node0 + l16;
    if (ar >= N) ar = N - 1;
    f32x4 accR[CT], accZ[CT], accN[CT], accH[CT];
#pragma unroll
    for (int t = 0; t < CT; ++t) {
        accR[t] = (f32x4){0.f, 0.f, 0.f, 0.f};
        accZ[t] = (f32x4){0.f, 0.f, 0.f, 0.f};
        accN[t] = (f32x4){0.f, 0.f, 0.f, 0.f};
        accH[t] = (f32x4){0.f, 0.f, 0.f, 0.f};
    }
    const short8* bhi = (const short8*)BsHi;
    const short8* blo = (const short8*)BsLo;
    int k0 = quad * 8;
    {  // ks = 0: S half (A=S_hi, B hi+lo: 2 ops)
        short8 ahi = *(const short8*)(Shi + (size_t)ar * C + k0);
#pragma unroll
        for (int g = 0; g < 3; ++g) {
            f32x4* acc = g == 0 ? accR : (g == 1 ? accZ : accN);
#pragma unroll
            for (int t = 0; t < CT; ++t) {
                int ts = g * CT + t;
                short8 bhf = bhi[(size_t)ts * 64 + lane];
                short8 blf = blo[(size_t)ts * 64 + lane];
                acc[t] = __builtin_amdgcn_mfma_f32_16x16x32_bf16(ahi, bhf, acc[t], 0, 0, 0);
                acc[t] = __builtin_amdgcn_mfma_f32_16x16x32_bf16(ahi, blf, acc[t], 0, 0, 0);
            }
        }
    }
    {  // ks = 1: H half (A=H_hi, B hi only: 1 op)
        short8 ahi = *(const short8*)(Hin + (size_t)ar * C + k0);
#pragma unroll
        for (int g = 0; g < 3; ++g) {
            f32x4* acc = g == 0 ? accR : (g == 1 ? accZ : accH);
#pragma unroll
            for (int t = 0; t < CT; ++t) {
                int ts = 3 * CT + g * CT + t;
                short8 bhf = bhi[(size_t)ts * 64 + lane];
                acc[t] = __builtin_amdgcn_mfma_f32_16x16x32_bf16(ahi, bhf, acc[t], 0, 0, 0);
            }
        }
    }
#pragma unroll
    for (int t = 0; t < CT; ++t) {
        int c = t * 16 + l16;
        float bir = biasI[c], biz = biasI[C + c], bin = biasI[2 * C + c];
        float bhr = biasH[c], bhz = biasH[C + c], bhn = biasH[2 * C + c];
#pragma unroll
        for (int r = 0; r < 4; ++r) {
            int node = node0 + quad * 4 + r;
            if (node < N) {
                size_t gi = (size_t)node * C + c;
                float xo = bf2f(Hin[gi]);
                float rv = sigmoid_f(accR[t][r] + bir + bhr);
                float zv = sigmoid_f(accZ[t][r] + biz + bhz);
                float nv = tanh_f(accN[t][r] + bin + rv * (accH[t][r] + bhn));
                Hout[gi] = f2bf((1.f - zv) * nv + zv * xo);
            }
        }
    }
}

// ------------------------- epilogues --------------------------------------

__global__ __launch_bounds__(256) void init_x_kernel(
    const float* __restrict__ x, unsigned short* __restrict__ H, int total) {
    int t = blockIdx.x * 256 + threadIdx.x;
    if (t < total) H[t] = f2bf(x[t]);
}

template <int Cin, int Cout>
__global__ __launch_bounds__(256) void elu_bn_pad_kernel(
    const unsigned short* __restrict__ S, unsigned short* __restrict__ D,
    const float* __restrict__ gamma, const float* __restrict__ beta,
    const float* __restrict__ mean, const float* __restrict__ var, int N) {
    long t = (long)blockIdx.x * 256 + threadIdx.x;
    long total = (long)N * Cout;
    if (t >= total) return;
    int n = (int)(t / Cout);
    int c = (int)(t & (Cout - 1));
    float v = 0.f;
    if (c < Cin) {
        size_t si = (size_t)n * Cin + c;
        float x = bf2f(S[si]);
        x = elu_f(x);
        v = (x - mean[c]) * rsqrtf(var[c] + EPS_BN) * gamma[c] + beta[c];
    }
    D[t] = f2bf(v);
}

// pool: batch sorted -> process node pairs, merge atomics when same graph
__global__ __launch_bounds__(256) void pool_elu_kernel(
    const unsigned short* __restrict__ H,
    const int* __restrict__ batch, float* __restrict__ G, int N) {
    long t = (long)blockIdx.x * 256 + threadIdx.x;
    long npairs = ((long)N + 1) >> 1;
    if (t >= npairs * 128) return;
    int pr = (int)(t >> 7);
    int c = (int)(t & 127);
    int n0 = pr * 2, n1 = n0 + 1;
    float v0 = elu_f(bf2f(H[(size_t)n0 * 128 + c]));
    int b0 = batch[n0];
    if (n1 < N) {
        float v1 = elu_f(bf2f(H[(size_t)n1 * 128 + c]));
        int b1 = batch[n1];
        if (b1 == b0) {
            atomicAdd(&G[b0 * 128 + c], v0 + v1);
            return;
        }
        atomicAdd(&G[b1 * 128 + c], v1);
    }
    atomicAdd(&G[b0 * 128 + c], v0);
}

__global__ __launch_bounds__(256) void fc1_kernel(
    const float* __restrict__ G, const float* __restrict__ W,
    const float* __restrict__ b, float* __restrict__ G2) {
    __shared__ float row[128];
    int g = blockIdx.x;
    int j = threadIdx.x;
    if (j < 128) row[j] = G[g * 128 + j];
    __syncthreads();
    float acc = b[j];
    for (int k = 0; k < 128; ++k) acc += row[k] * W[j * 128 + k];
    G2[g * 256 + j] = elu_f(acc);
}

__global__ __launch_bounds__(64) void fc2_logsoftmax_kernel(
    const float* __restrict__ G2, const float* __restrict__ W,
    const float* __restrict__ b, float* __restrict__ out) {
    __shared__ float row[256];
    __shared__ float logits[10];
    __shared__ float red[2];
    int g = blockIdx.x;
    int tid = threadIdx.x;
    for (int i = tid; i < 256; i += 64) row[i] = G2[g * 256 + i];
    __syncthreads();
    if (tid < 10) {
        float acc = b[tid];
        for (int k = 0; k < 256; ++k) acc += row[k] * W[tid * 256 + k];
        logits[tid] = acc;
    }
    __syncthreads();
    if (tid == 0) {
        float m = -1e30f;
        for (int a = 0; a < 10; ++a) m = fmaxf(m, logits[a]);
        float s = 0.f;
        for (int a = 0; a < 10; ++a) s += expf(logits[a] - m);
        red[0] = m;
        red[1] = logf(s);
    }
    __syncthreads();
    if (tid < 10) out[g * 10 + tid] = logits[tid] - red[0] - red[1];
}

// ---------------------------------------------------------------------------

template <int C>
static void run_conv(unsigned short* A, unsigned short* B,
                     unsigned short* Shi,
                     const unsigned short* BsHi, const unsigned short* BsLo,
                     const float* bih, const float* bhh,
                     const int* rowstart, const int* csr_src,
                     int N, int E, hipStream_t stream) {
    constexpr int NT = (C == 128) ? 32 : 64;  // nodes per GRU block
    int nb = (N + NT - 1) / NT;
    constexpr int GPB = 2048 / C;  // gather dst-groups per block (C/8 lanes)
    int gblocks = (N + GPB - 1) / GPB;
    unsigned short *in = A, *out = B;
    for (int it = 0; it < 4; ++it) {
        gather_kernel<C><<<gblocks, 256, 0, stream>>>(
            in, rowstart, csr_src, Shi, N);
        const unsigned short* bs_h = BsHi + (size_t)it * 6 * C * C;
        const unsigned short* bs_l = BsLo + (size_t)it * 6 * C * C;
        if constexpr (C == 32)
            gru32_kernel<<<nb, 256, 0, stream>>>(
                in, out, Shi, bs_h, bs_l, bih, bhh, N);
        else
            gru_mfma_kernel<C, NT, 3><<<nb, 256, 0, stream>>>(
                in, out, Shi, bs_h, bs_l, bih, bhh, N);
        unsigned short* tp = in; in = out; out = tp;
    }
    // 4 iterations (even) -> final state back in A
}

extern "C" void kernel_launch(void* const* d_in, const int* in_sizes, int n_in,
                              void* d_out, int out_size, void* d_ws, size_t ws_size,
                              hipStream_t stream) {
    const float* x = (const float*)d_in[0];
    const int* ei = (const int*)d_in[1];
    const int* batch = (const int*)d_in[2];
    const float* fc1W = (const float*)d_in[3];
    const float* fc1b = (const float*)d_in[4];
    const float* fc2W = (const float*)d_in[5];
    const float* fc2b = (const float*)d_in[6];
    const float* c1W = (const float*)d_in[7];
    const float* c1wih = (const float*)d_in[8];
    const float* c1whh = (const float*)d_in[9];
    const float* c1bih = (const float*)d_in[10];
    const float* c1bhh = (const float*)d_in[11];
    const float* c2W = (const float*)d_in[12];
    const float* c2wih = (const float*)d_in[13];
    const float* c2whh = (const float*)d_in[14];
    const float* c2bih = (const float*)d_in[15];
    const float* c2bhh = (const float*)d_in[16];
    const float* c3W = (const float*)d_in[17];
    const float* c3wih = (const float*)d_in[18];
    const float* c3whh = (const float*)d_in[19];
    const float* c3bih = (const float*)d_in[20];
    const float* c3bhh = (const float*)d_in[21];
    const float* bn1g = (const float*)d_in[22];
    const float* bn1b = (const float*)d_in[23];
    const float* bn1m = (const float*)d_in[24];
    const float* bn1v = (const float*)d_in[25];
    const float* bn2g = (const float*)d_in[26];
    const float* bn2b = (const float*)d_in[27];
    const float* bn2m = (const float*)d_in[28];
    const float* bn2v = (const float*)d_in[29];

    int N = in_sizes[0] / 32;
    int E = in_sizes[1] / 2;

    const size_t NB = (size_t)N * 128;  // shorts per plane
    unsigned short* PA = (unsigned short*)d_ws;    // state A (single plane)
    unsigned short* PB = PA + NB;                  // state B (ping-pong)
    unsigned short* Shi = PB + NB;                 // gathered-S (hi-only)
    unsigned short* BsHi = Shi + NB;               // all 3 convs: 516096 shorts
    unsigned short* BsLo = BsHi + 516096;
    float* Wc = (float*)(BsLo + 516096);           // all 3 convs: 258048 floats
    float* G = Wc + 258048;
    float* G2 = G + 32768;
    int* deg = (int*)(G2 + 65536);
    int* scanout = deg + N;
    int* rowstart = scanout + N;
    int* writeptr = rowstart + N + 1;
    int* blockSums = writeptr + N;
    int* csr_src = blockSums + 64;

    // ---- weight prep for all 3 convs (2 dispatches, r27) ----
    wc_all_kernel<<<(258048 + 255) / 256, 256, 0, stream>>>(
        c1W, c1wih, c2W, c2wih, c3W, c3wih, Wc);
    swizzle_all_kernel<<<(516096 + 255) / 256, 256, 0, stream>>>(
        Wc, c1whh, c2whh, c3whh, BsHi, BsLo);

    // ---- build CSR by dst (once; reused by all 12 propagation steps) ----
    hipMemsetAsync(deg, 0, (size_t)N * sizeof(int), stream);
    hist_kernel<<<2048, 256, 0, stream>>>(ei, deg, E, N);
    int nscan = (N + 1023) / 1024;
    scan1_kernel<<<nscan, 256, 0, stream>>>(deg, scanout, blockSums, N);
    scan2_kernel<<<1, 64, 0, stream>>>(blockSums, nscan);
    scan3_kernel<<<(N + 255) / 256, 256, 0, stream>>>(scanout, blockSums, rowstart, writeptr, N, E);
    fill_kernel<<<2048, 256, 0, stream>>>(ei, writeptr, csr_src, E, N);

    // x -> state A ([N,32] bf16)
    init_x_kernel<<<(N * 32 + 255) / 256, 256, 0, stream>>>(x, PA, N * 32);

    // conv1 (C=32): state PA, ping-pong with PB
    run_conv<32>(PA, PB, Shi, BsHi, BsLo,
                 c1bih, c1bhh, rowstart, csr_src, N, E, stream);
    elu_bn_pad_kernel<32, 64><<<(int)(((long)N * 64 + 255) / 256), 256, 0, stream>>>(
        PA, PB, bn1g, bn1b, bn1m, bn1v, N);

    // conv2 (C=64): state PB, ping-pong with PA
    run_conv<64>(PB, PA, Shi, BsHi + 24576, BsLo + 24576,
                 c2bih, c2bhh, rowstart, csr_src, N, E, stream);
    elu_bn_pad_kernel<64, 128><<<(int)(((long)N * 128 + 255) / 256), 256, 0, stream>>>(
        PB, PA, bn2g, bn2b, bn2m, bn2v, N);

    // conv3 (C=128): state PA, ping-pong with PB
    run_conv<128>(PA, PB, Shi, BsHi + 122880, BsLo + 122880,
                  c3bih, c3bhh, rowstart, csr_src, N, E, stream);

    // pool (reads state PA, stride 128)
    hipMemsetAsync(G, 0, 256 * 128 * sizeof(float), stream);
    {
        long npairs = ((long)N + 1) >> 1;
        pool_elu_kernel<<<(int)((npairs * 128 + 255) / 256), 256, 0, stream>>>(
            PA, batch, G, N);
    }

    fc1_kernel<<<256, 256, 0, stream>>>(G, fc1W, fc1b, G2);
    fc2_logsoftmax_kernel<<<256, 64, 0, stream>>>(G2, fc2W, fc2b, (float*)d_out);
}